// Round 5
// baseline (493.283 us; speedup 1.0000x reference)
//
#include <hip/hip_runtime.h>

typedef unsigned short u16;
typedef short bf16x8 __attribute__((ext_vector_type(8)));
typedef float f32x4 __attribute__((ext_vector_type(4)));

#define HN 16
#define SD 64
#define SEQ 2048
#define DM 1024
#define QSC 0.18033688f  // 0.125 * log2(e): softmax done in exp2 domain

__device__ __forceinline__ float bf2f(u16 h) {
  return __uint_as_float(((unsigned int)h) << 16);
}
__device__ __forceinline__ u16 f2bf(float f) {
  unsigned int x = __float_as_uint(f);
  x += 0x7fffu + ((x >> 16) & 1u);
  return (u16)(x >> 16);
}
__device__ __forceinline__ float geluf(float x) {
  return 0.5f * x * (1.0f + erff(x * 0.70710678118654752f));
}
__device__ __forceinline__ void load_lds16(const u16* g, u16* l) {
  __builtin_amdgcn_global_load_lds(
      (const __attribute__((address_space(1))) void*)g,
      (__attribute__((address_space(3))) void*)l, 16, 0, 0);
}
// LDS byte offset of a generic pointer known to point into LDS.
__device__ __forceinline__ unsigned ldsoff(const u16* p) {
  return (unsigned)(unsigned long long)(
      const __attribute__((address_space(3))) u16*)p;
}

// ----------------------------------------------------- transpose tile (dev)
__device__ __forceinline__ void trans_tile(const float* __restrict__ in,
                                           u16* __restrict__ out, int K, int N,
                                           int tx, int ty, int tid,
                                           u16 (*T)[72]) {
  const int n0 = tx * 64, k0 = ty * 64;
#pragma unroll
  for (int it = 0; it < 2; ++it) {
    const int t = it * 256 + tid, r = t >> 3, c = (t & 7) * 8;
    const float* src = &in[(size_t)(k0 + r) * N + n0 + c];
    float4 d0 = *(const float4*)src;
    float4 d1 = *(const float4*)(src + 4);
    T[r][c + 0] = f2bf(d0.x);
    T[r][c + 1] = f2bf(d0.y);
    T[r][c + 2] = f2bf(d0.z);
    T[r][c + 3] = f2bf(d0.w);
    T[r][c + 4] = f2bf(d1.x);
    T[r][c + 5] = f2bf(d1.y);
    T[r][c + 6] = f2bf(d1.z);
    T[r][c + 7] = f2bf(d1.w);
  }
  __syncthreads();
#pragma unroll
  for (int it = 0; it < 2; ++it) {
    const int t = it * 256 + tid, r = t >> 3, c = (t & 7) * 8;
    uint4 d;
    u16* p = (u16*)&d;
#pragma unroll
    for (int j = 0; j < 8; ++j) p[j] = T[c + j][r];
    *(uint4*)&out[(size_t)(n0 + r) * K + k0 + c] = d;
  }
}

// ------------------------------------------------- prep1: 6 WT + mem f2b
__global__ __launch_bounds__(256) void prep1(
    const float* __restrict__ Wqkv, const float* __restrict__ Wo,
    const float* __restrict__ Wqc, const float* __restrict__ Wkc,
    const float* __restrict__ Wvc, const float* __restrict__ Wco,
    u16* __restrict__ Tqkv, u16* __restrict__ To, u16* __restrict__ Tqc,
    u16* __restrict__ Tkc, u16* __restrict__ Tvc, u16* __restrict__ Tco,
    const float* __restrict__ mem, u16* __restrict__ memb) {
  __shared__ u16 T[64][72];
  const int t = blockIdx.x, tid = threadIdx.x;
  if (t < 768) {
    trans_tile(Wqkv, Tqkv, 1024, 3072, t % 48, t / 48, tid, T);
    return;
  }
  if (t < 2048) {
    const int u = t - 768, m = u >> 8, sub = u & 255;
    const float* in;
    u16* out;
    if (m == 0) { in = Wo; out = To; }
    else if (m == 1) { in = Wqc; out = Tqc; }
    else if (m == 2) { in = Wkc; out = Tkc; }
    else if (m == 3) { in = Wvc; out = Tvc; }
    else { in = Wco; out = Tco; }
    trans_tile(in, out, 1024, 1024, sub & 15, sub >> 4, tid, T);
    return;
  }
  const int i = ((t - 2048) * 256 + tid) * 4;
  float4 d = *(const float4*)&mem[i];
  uint2 o;
  u16* po = (u16*)&o;
  po[0] = f2bf(d.x);
  po[1] = f2bf(d.y);
  po[2] = f2bf(d.z);
  po[3] = f2bf(d.w);
  *(uint2*)&memb[i] = o;
}

// ------------------------------------------------- prep2: W1 + W2 transpose
__global__ __launch_bounds__(256) void prep2(const float* __restrict__ W1,
                                             const float* __restrict__ W2,
                                             u16* __restrict__ T1,
                                             u16* __restrict__ T2) {
  __shared__ u16 T[64][72];
  const int t = blockIdx.x, tid = threadIdx.x;
  if (t < 1024) {
    trans_tile(W1, T1, 1024, 4096, t & 63, t >> 6, tid, T);
  } else {
    const int u = t - 1024;
    trans_tile(W2, T2, 4096, 1024, u & 15, u >> 4, tid, T);
  }
}

// ---------------------------------------------------------------- layernorm
__global__ __launch_bounds__(256) void ln_kernel(
    const float* __restrict__ x, const float* __restrict__ g,
    const float* __restrict__ be, u16* __restrict__ y) {
  const int row = blockIdx.x, tid = threadIdx.x;
  const float* xr = x + (size_t)row * DM;
  float4 d = *(const float4*)&xr[tid * 4];
  float v[4] = {d.x, d.y, d.z, d.w};
  float s1 = 0.f, s2 = 0.f;
#pragma unroll
  for (int j = 0; j < 4; ++j) {
    s1 += v[j];
    s2 += v[j] * v[j];
  }
#pragma unroll
  for (int dd = 1; dd < 64; dd <<= 1) {
    s1 += __shfl_xor(s1, dd, 64);
    s2 += __shfl_xor(s2, dd, 64);
  }
  __shared__ float p1[4], p2[4];
  const int lane = tid & 63, wv = tid >> 6;
  if (lane == 0) {
    p1[wv] = s1;
    p2[wv] = s2;
  }
  __syncthreads();
  s1 = p1[0] + p1[1] + p1[2] + p1[3];
  s2 = p2[0] + p2[1] + p2[2] + p2[3];
  const float mu = s1 * (1.f / DM);
  const float rs = rsqrtf(fmaxf(s2 * (1.f / DM) - mu * mu, 0.f) + 1e-5f);
  float4 gg = *(const float4*)&g[tid * 4];
  float4 bb = *(const float4*)&be[tid * 4];
  const float gv[4] = {gg.x, gg.y, gg.z, gg.w};
  const float bv[4] = {bb.x, bb.y, bb.z, bb.w};
  uint2 o;
  u16* po = (u16*)&o;
#pragma unroll
  for (int j = 0; j < 4; ++j) po[j] = f2bf((v[j] - mu) * rs * gv[j] + bv[j]);
  *(uint2*)&y[(size_t)row * DM + tid * 4] = o;
}

// ---------------------------------------------------------------- GEMM (r0)
// 2-barrier single-buffer structure for the small/odd-shaped GEMMs.
template <int EPI, int TM>
__global__ __launch_bounds__(256) void gemm_bt(
    const u16* __restrict__ A, const u16* __restrict__ Bt,
    const float* __restrict__ bias, const float* __restrict__ resid,
    void* __restrict__ C0, u16* __restrict__ C1, u16* __restrict__ C2, int M,
    int N, int K, int rpbl, float sc, const float* __restrict__ rcos,
    const float* __restrict__ rsin) {
  constexpr int MI = TM / 32;
  __shared__ __align__(16) u16 As[TM][64];
  __shared__ __align__(16) u16 Bs[128][64];
  const int tid = threadIdx.x;
  const int lane = tid & 63, wv = tid >> 6;
  const int l16 = lane & 15, quad = lane >> 4;

  if (EPI == 6 && blockIdx.z) {
    Bt = (const u16*)C1;
    bias = resid;
  }

  int bx = blockIdx.x, by = blockIdx.y;
  const int gx = gridDim.x, gy = gridDim.y;
  if ((gy & 7) == 0) {
    const int f = by * gx + bx;
    const int c = f & 7, j = f >> 3;
    const int jm = j / gx;
    by = c * (gy >> 3) + jm;
    bx = j - jm * gx;
  }
  const int m0 = by * TM, n0 = bx * 128;
  const int wm = (wv >> 1) * (TM / 2), wn = (wv & 1) * 64;

  const int srow = lane >> 3;
  const int sblk = (lane & 7) ^ srow;
  const u16* ag[MI];
  const u16* bg[4];
  u16* la[MI];
  u16* lb[4];
#pragma unroll
  for (int i = 0; i < MI; ++i) {
    const int r0 = i * 32 + wv * 8;
    ag[i] = A + (size_t)(m0 + r0 + srow) * K + sblk * 8;
    la[i] = &As[r0][0] + lane * 8;
  }
#pragma unroll
  for (int i = 0; i < 4; ++i) {
    const int r0 = i * 32 + wv * 8;
    bg[i] = Bt + (size_t)(n0 + r0 + srow) * K + sblk * 8;
    lb[i] = &Bs[r0][0] + lane * 8;
  }

  f32x4 acc[MI][4] = {};

  for (int k0 = 0; k0 < K; k0 += 64) {
    __syncthreads();
#pragma unroll
    for (int i = 0; i < MI; ++i) load_lds16(ag[i] + k0, la[i]);
#pragma unroll
    for (int i = 0; i < 4; ++i) load_lds16(bg[i] + k0, lb[i]);
    __syncthreads();
#pragma unroll
    for (int kk = 0; kk < 2; ++kk) {
      bf16x8 af[MI], bfr[4];
#pragma unroll
      for (int mi = 0; mi < MI; ++mi) {
        const int row = wm + mi * 16 + l16;
        const int blk = (kk * 4 + quad) ^ (row & 7);
        af[mi] = *(const bf16x8*)&As[row][blk * 8];
      }
#pragma unroll
      for (int ni = 0; ni < 4; ++ni) {
        const int row = wn + ni * 16 + l16;
        const int blk = (kk * 4 + quad) ^ (row & 7);
        bfr[ni] = *(const bf16x8*)&Bs[row][blk * 8];
      }
#pragma unroll
      for (int mi = 0; mi < MI; ++mi)
#pragma unroll
        for (int ni = 0; ni < 4; ++ni)
          acc[mi][ni] = __builtin_amdgcn_mfma_f32_16x16x32_bf16(
              af[mi], bfr[ni], acc[mi][ni], 0, 0, 0);
    }
  }

  const int SL = 1 << rpbl;
#pragma unroll
  for (int mi = 0; mi < MI; ++mi) {
#pragma unroll
    for (int ni = 0; ni < 4; ++ni) {
#pragma unroll
      for (int r = 0; r < 4; ++r) {
        const int row = m0 + wm + mi * 16 + quad * 4 + r;
        const int col = n0 + wn + ni * 16 + l16;
        float vv = acc[mi][ni][r] + bias[col];
        if (EPI == 1) {
          vv += resid[(size_t)row * N + col];
          ((float*)C0)[(size_t)row * N + col] = vv;
        } else if (EPI == 2) {
          ((u16*)C0)[(size_t)row * N + col] = f2bf(geluf(vv));
        } else if (EPI == 3) {
          const float partner = __shfl_xor(vv, 1);
          const int which = col >> 10;
          const int nn = col & 1023;
          const int h = nn >> 6, hd = nn & 63;
          const int b = row >> rpbl;
          const int s = row & (SL - 1);
          if (which == 2) {
            C2[(((size_t)b * HN + h) * SD + hd) * SL + s] = f2bf(vv);
          } else {
            const int p = hd >> 1;
            const float cv = rcos[s * 32 + p];
            const float sv2 = rsin[s * 32 + p];
            float o = (hd & 1) ? (partner * sv2 + vv * cv)
                               : (vv * cv - partner * sv2);
            if (which == 0) o *= QSC;
            u16* dst = (which == 0) ? (u16*)C0 : C1;
            dst[(((size_t)b * HN + h) * SL + s) * SD + hd] = f2bf(o);
          }
        } else if (EPI == 4) {
          vv *= sc;
          const int h = col >> 6, hd = col & 63;
          const int b = row >> rpbl;
          const int s = row & (SL - 1);
          ((u16*)C0)[(((size_t)b * HN + h) * SL + s) * SD + hd] = f2bf(vv);
        } else if (EPI == 5) {
          const int h = col >> 6, hd = col & 63;
          const int b = row >> rpbl;
          const int s = row & (SL - 1);
          ((u16*)C0)[(((size_t)b * HN + h) * SD + hd) * SL + s] = f2bf(vv);
        } else if (EPI == 6) {
          const int h = col >> 6, hd = col & 63;
          const int b = row >> rpbl;
          const int s = row & (SL - 1);
          if (blockIdx.z == 0)
            ((u16*)C0)[(((size_t)b * HN + h) * SL + s) * SD + hd] = f2bf(vv);
          else
            C2[(((size_t)b * HN + h) * SD + hd) * SL + s] = f2bf(vv);
        } else {
          ((u16*)C0)[(size_t)row * N + col] = f2bf(vv);
        }
      }
    }
  }
}

// ---------------------------------------------------------------- GEMM 8p
// r12: 256 x (NI*64) tile, BK=64, 8 waves (2M x 4N), 512 thr, 1 block/CU.
// TWO fat phases per K-tile (was 4 thin): each phase = 12 ds_read_b128 +
// 2 half-tile stages (4 loads) + 32|24 MFMA + vmcnt(8) + 2 barriers.
// Halves the per-tile barrier/wait overhead (r9-r11 pinned ~2600cyc/phase
// regardless of wait scheme => fixed-overhead hypothesis). NI=3 gives
// BN=192 so QKV (N=3072) gets grid 16x16=256 blocks (all CUs; was 192
// blocks idling 25% of the chip -- FFN1-vs-QKV per-CU rates proved this).
// Schedule: P1(t): read kk0(t), stage A1B1(t+1); P2(t): read kk1(t),
// stage A0B0(t+2). vmcnt(8) at every phase end retires exactly the halves
// the next phase reads (issue-order verified); region overwrite is
// barrier-protected (stores issued only after last reader's phase barrier).
template <int EPI, int NI>
__global__ __launch_bounds__(512, 2) void gemm8p(
    const u16* __restrict__ A, const u16* __restrict__ Bt,
    const float* __restrict__ bias, void* __restrict__ C0,
    u16* __restrict__ C1, u16* __restrict__ C2, int M, int N, int K, int rpbl,
    const float* __restrict__ rcos, const float* __restrict__ rsin) {
  __shared__ __align__(16) u16 L[4][2][8192];  // [A0,A1,B0,B1][buf][128x64]
  const int tid = threadIdx.x;
  const int lane = tid & 63, wv = tid >> 6;
  const int l16 = lane & 15, quad = lane >> 4;
  int bx = blockIdx.x, by = blockIdx.y;
  {  // bijective XCD chunk swizzle (nwg % 8 == 0 for all our grids)
    const int gx = gridDim.x;
    const int nwg = gx * gridDim.y;
    if ((nwg & 7) == 0) {
      const int f = by * gx + bx;
      const int q = nwg >> 3;
      const int wg = (f & 7) * q + (f >> 3);
      by = wg / gx;
      bx = wg - by * gx;
    }
  }
  const int m0 = by * 256, n0 = bx * (NI * 64);
  const int wm = (wv >> 2) * 128, wn = (wv & 3) * (NI * 16);
  const int nk = K >> 6;

  const u16* Ag = A + (size_t)m0 * K;
  const u16* Bg = Bt + (size_t)n0 * K;

// STAGE: literal mat/h/parity -> fully static LDS destination. For NI=3 the
// B rows 192..255 staged here are never read as fragments (wn+ni*16+l16 <
// 192); their global source stays inside d_ws (next workspace region).
#define STAGE(MAT, H, ST, P)                                                  \
  {                                                                           \
    const int tt = (ST) < nk ? (ST) : nk - 1; /* clamp: dummy loads */        \
    const int k0s = tt << 6;                                                  \
    u16* dst = &L[(MAT)*2 + (H)][P][0];                                       \
    const u16* srcp = (MAT) ? Bg : Ag;                                        \
    _Pragma("unroll") for (int j = 0; j < 2; ++j) {                           \
      const int li = wv * 2 + j;                                              \
      const int pr = li * 8 + (lane >> 3);                                    \
      const int bb = lane & 7;                                                \
      const int gg2 = bb ^ (pr & 7);                                          \
      const int rw = 2 * pr + (gg2 >> 2);                                     \
      load_lds16(srcp + (size_t)rw * K + k0s + (H)*32 + (gg2 & 3) * 8,        \
                 dst + li * 512 + lane * 8);                                  \
    }                                                                         \
  }

  // precomputed per-thread LDS byte addresses (buf0, half0); CB/KK add an
  // immediate: A(kk,cb) at (kk*2+cb)*16384, B(kk,cb) at 65536+same.
  unsigned aaddr[2][4], baddr[NI];
  {
    const unsigned Lb = ldsoff(&L[0][0][0]);
#pragma unroll
    for (int MH = 0; MH < 2; ++MH)
#pragma unroll
      for (int mi = 0; mi < 4; ++mi) {
        const int R = wm + MH * 64 + mi * 16 + l16;
        const int p = R >> 1, g = (R & 1) * 4 + quad, b = g ^ (p & 7);
        aaddr[MH][mi] = Lb + (unsigned)(p * 64 + b * 8) * 2u;
      }
#pragma unroll
    for (int ni = 0; ni < NI; ++ni) {
      const int R = wn + ni * 16 + l16;
      const int p = R >> 1, g = (R & 1) * 4 + quad, b = g ^ (p & 7);
      baddr[ni] = Lb + 65536u + (unsigned)(p * 64 + b * 8) * 2u;
    }
  }

  f32x4 acc[8][NI] = {};

// One fat phase: read all frags for (CB,KK), stage two half-tiles, barrier,
// wait, 8xNI MFMA, counted vmcnt, barrier.
#define PHASE(CB, KK, S1M, S1H, S2M, S2H, ST, SP)                             \
  {                                                                           \
    bf16x8 af[2][4];                                                          \
    bf16x8 bfr[NI];                                                           \
    _Pragma("unroll") for (int mh = 0; mh < 2; ++mh)                          \
        _Pragma("unroll") for (int mi = 0; mi < 4; ++mi)                      \
            asm volatile("ds_read_b128 %0, %1 offset:%2"                      \
                         : "=v"(af[mh][mi])                                   \
                         : "v"(aaddr[mh][mi]),                                \
                           "i"((KK)*32768 + (CB)*16384));                     \
    _Pragma("unroll") for (int ni = 0; ni < NI; ++ni)                         \
        asm volatile("ds_read_b128 %0, %1 offset:%2"                          \
                     : "=v"(bfr[ni])                                          \
                     : "v"(baddr[ni]), "i"((KK)*32768 + (CB)*16384));         \
    STAGE(S1M, S1H, ST, SP);                                                  \
    STAGE(S2M, S2H, ST, SP);                                                  \
    __builtin_amdgcn_s_barrier();                                             \
    asm volatile("s_waitcnt lgkmcnt(0)");                                     \
    __builtin_amdgcn_sched_barrier(0);                                        \
    __builtin_amdgcn_s_setprio(1);                                            \
    _Pragma("unroll") for (int mh = 0; mh < 2; ++mh)                          \
        _Pragma("unroll") for (int mi = 0; mi < 4; ++mi)                      \
            _Pragma("unroll") for (int ni = 0; ni < NI; ++ni)                 \
                acc[mh * 4 + mi][ni] =                                        \
                    __builtin_amdgcn_mfma_f32_16x16x32_bf16(                  \
                        af[mh][mi], bfr[ni], acc[mh * 4 + mi][ni], 0, 0, 0);  \
    __builtin_amdgcn_s_setprio(0);                                            \
    asm volatile("s_waitcnt vmcnt(8)");                                       \
    __builtin_amdgcn_s_barrier();                                             \
  }

  // prologue: A0B0(t0), A1B1(t0), A0B0(t1) = 12 loads/thread; retire first 4
  // (A0B0(t0)) via vmcnt(8).
  STAGE(0, 0, 0, 0);
  STAGE(1, 0, 0, 0);
  STAGE(0, 1, 0, 0);
  STAGE(1, 1, 0, 0);
  STAGE(0, 0, 1, 1);
  STAGE(1, 0, 1, 1);
  asm volatile("s_waitcnt vmcnt(8)");
  __builtin_amdgcn_s_barrier();

  for (int t = 0; t < nk; t += 2) {  // nk even for all our shapes
    // tile t (buf 0)
    PHASE(0, 0, 0, 1, 1, 1, t + 1, 1)  // read kk0; stage A1B1(t+1)->buf1
    PHASE(0, 1, 0, 0, 1, 0, t + 2, 0)  // read kk1; stage A0B0(t+2)->buf0
    // tile t+1 (buf 1)
    PHASE(1, 0, 0, 1, 1, 1, t + 2, 0)  // read kk0; stage A1B1(t+2)->buf0
    PHASE(1, 1, 0, 0, 1, 0, t + 3, 1)  // read kk1; stage A0B0(t+3)->buf1
  }
#undef PHASE
#undef STAGE

  const int SL = 1 << rpbl;
#pragma unroll
  for (int mi = 0; mi < 8; ++mi) {
#pragma unroll
    for (int ni = 0; ni < NI; ++ni) {
#pragma unroll
      for (int r = 0; r < 4; ++r) {
        const int row = m0 + wm + mi * 16 + quad * 4 + r;
        const int col = n0 + wn + ni * 16 + l16;
        float vv = acc[mi][ni][r] + bias[col];
        if (EPI == 2) {
          ((u16*)C0)[(size_t)row * N + col] = f2bf(geluf(vv));
        } else if (EPI == 3) {
          const float partner = __shfl_xor(vv, 1);
          const int which = col >> 10;
          const int nn = col & 1023;
          const int h = nn >> 6, hd = nn & 63;
          const int b = row >> rpbl;
          const int s = row & (SL - 1);
          if (which == 2) {
            C2[(((size_t)b * HN + h) * SD + hd) * SL + s] = f2bf(vv);
          } else {
            const int p = hd >> 1;
            const float cv = rcos[s * 32 + p];
            const float sv2 = rsin[s * 32 + p];
            float o = (hd & 1) ? (partner * sv2 + vv * cv)
                               : (vv * cv - partner * sv2);
            if (which == 0) o *= QSC;
            u16* dst = (which == 0) ? (u16*)C0 : C1;
            dst[(((size_t)b * HN + h) * SL + s) * SD + hd] = f2bf(o);
          }
        } else {
          ((u16*)C0)[(size_t)row * N + col] = f2bf(vv);
        }
      }
    }
  }
}

// ---------------------------------------------------------------- attention
template <int CAUSAL>
__global__ __launch_bounds__(512, 4) void attn_kernel(
    const u16* __restrict__ q, const u16* __restrict__ k,
    const u16* __restrict__ vt, u16* __restrict__ out, int kv_len) {
  __shared__ u16 Qs[128][72], Ks[64][72], VTs[64][72];
  __shared__ u16 Ps[128][68];
  const int tid = threadIdx.x;
  const int lane = tid & 63, wv = tid >> 6;
  const int t2 = wv >> 2, w4 = wv & 3;
  const int l16 = lane & 15, quad = lane >> 4;
  const int bx = blockIdx.x, bh = blockIdx.y;
  const int qtA = bx;
  const int qtB = CAUSAL ? (31 - bx) : (bx + 16);
  const int qt = t2 ? qtB : qtA;
  const u16* qb = q + (size_t)bh * SEQ * SD;
  const u16* kb = k + (size_t)bh * kv_len * SD;
  const u16* vtb = vt + (size_t)bh * SD * kv_len;

#pragma unroll
  for (int it = 0; it < 2; ++it) {
    const int t = it * 512 + tid, r = t >> 3, c = (t & 7) * 8;
    const int qrow = (r < 64) ? (qtA * 64 + r) : (qtB * 64 + (r - 64));
    *(uint4*)&Qs[r][c] = *(const uint4*)&qb[(size_t)qrow * SD + c];
  }

  f32x4 o_acc[4] = {};
  float l_i[4] = {};

  const int ktiles = CAUSAL ? (qtB + 1) : ((kv_len + 63) >> 6);
  const int sr = tid >> 3, sc8 = (tid & 7) * 8;

  for (int kt = 0; kt < ktiles; ++kt) {
    const uint4 kd = *(const uint4*)&kb[((size_t)kt * 64 + sr) * SD + sc8];
    const uint4 vd = *(const uint4*)&vtb[(size_t)sr * kv_len + kt * 64 + sc8];
    __syncthreads();
    *(uint4*)&Ks[sr][sc8] = kd;
    *(uint4*)&VTs[sr][sc8] = vd;
    __syncthreads();

    if (kt <= qt) {
      const int roff = t2 * 64 + w4 * 16;
      f32x4 s_acc[4] = {};
#pragma unroll
      for (int kk = 0; kk < 64; kk += 32) {
        const bf16x8 aq = *(const bf16x8*)&Qs[roff + l16][kk + quad * 8];
#pragma unroll
        for (int ni = 0; ni < 4; ++ni) {
          const bf16x8 bk = *(const bf16x8*)&Ks[ni * 16 + l16][kk + quad * 8];
          s_acc[ni] = __builtin_amdgcn_mfma_f32_16x16x32_bf16(aq, bk, s_acc[ni],
                                                              0, 0, 0);
        }
      }
      float rsum[4] = {0.f, 0.f, 0.f, 0.f};
      const bool dg = CAUSAL && (kt == qt);
#pragma unroll
      for (int ni = 0; ni < 4; ++ni)
#pragma unroll
        for (int r = 0; r < 4; ++r) {
          float sv = s_acc[ni][r];
          if (dg && (ni * 16 + l16 > w4 * 16 + quad * 4 + r)) sv = -1e9f;
          const float pe = __builtin_amdgcn_exp2f(sv);
          rsum[r] += pe;
          Ps[wv * 16 + quad * 4 + r][ni * 16 + l16] =
              (u16)(__float_as_uint(pe) >> 16);
        }
#pragma unroll
      for (int r = 0; r < 4; ++r) {
#pragma unroll
        for (int dd = 1; dd < 16; dd <<= 1)
          rsum[r] += __shfl_xor(rsum[r], dd, 64);
        l_i[r] += rsum[r];
      }
#pragma unroll
      for (int kk = 0; kk < 64; kk += 32) {
        const bf16x8 ap = *(const bf16x8*)&Ps[wv * 16 + l16][kk + quad * 8];
#pragma unroll
        for (int ni = 0; ni < 4; ++ni) {
          const bf16x8 bv = *(const bf16x8*)&VTs[ni * 16 + l16][kk + quad * 8];
          o_acc[ni] = __builtin_amdgcn_mfma_f32_16x16x32_bf16(ap, bv, o_acc[ni],
                                                              0, 0, 0);
        }
      }
    }
  }

  const int b = bh >> 4, h = bh & 15;
#pragma unroll
  for (int r = 0; r < 4; ++r) {
    const float inv = 1.f / l_i[r];
    const int s = qt * 64 + w4 * 16 + quad * 4 + r;
#pragma unroll
    for (int ni = 0; ni < 4; ++ni)
      out[((size_t)b * SEQ + s) * DM + h * SD + ni * 16 + l16] =
          f2bf(o_acc[ni][r] * inv);
  }
}

// ---------------------------------------------------------------- launch
extern "C" void kernel_launch(void* const* d_in, const int* in_sizes, int n_in,
                              void* d_out, int out_size, void* d_ws,
                              size_t ws_size, hipStream_t stream) {
  (void)in_sizes;
  (void)n_in;
  (void)out_size;
  (void)ws_size;
  const float* tgt = (const float*)d_in[0];
  const float* mem = (const float*)d_in[1];
  const float* rc = (const float*)d_in[2];
  const float* rsn = (const float*)d_in[3];
  const float* W_qkv = (const float*)d_in[4];
  const float* b_qkv = (const float*)d_in[5];
  const float* W_o = (const float*)d_in[6];
  const float* b_o = (const float*)d_in[7];
  const float* Wq_c = (const float*)d_in[8];
  const float* bq_c = (const float*)d_in[9];
  const float* Wk_c = (const float*)d_in[10];
  const float* bk_c = (const float*)d_in[11];
  const float* Wv_c = (const float*)d_in[12];
  const float* bv_c = (const float*)d_in[13];
  const float* W_co = (const float*)d_in[14];
  const float* b_co = (const float*)d_in[15];
  const float* W1 = (const float*)d_in[16];
  const float* b1 = (const float*)d_in[17];
  const float* W2 = (const float*)d_in[18];
  const float* b2 = (const float*)d_in[19];
  const float* g1 = (const float*)d_in[20];
  const float* be1 = (const float*)d_in[21];
  const float* g2 = (const float*)d_in[22];
  const float* be2 = (const float*)d_in[23];
  const float* g3 = (const float*)d_in[24];
  const float* be3 = (const float*)d_in[25];

  const size_t M1 = 1048576;
  u16* w = (u16*)d_ws;
  u16* WTqkv = w;
  u16* WTo = w + 3 * M1;
  u16* WTqc = w + 4 * M1;
  u16* WTkc = w + 5 * M1;
  u16* WTvc = w + 6 * M1;
  u16* WTco = w + 7 * M1;
  u16* WT1 = w;
  u16* WT2 = w + 4 * M1;
  u16* xb = w + 8 * M1;
  u16* qb = w + 12 * M1;
  u16* kb = w + 16 * M1;
  u16* vbT = w + 20 * M1;
  u16* at = w + 24 * M1;
  u16* kc = w + 28 * M1;
  u16* vcT = kc + 131072;
  u16* memb = vcT + 131072;
  u16* ffh = qb;
  float* res = (float*)d_out;

  dim3 blk(256), blk512(512);
  prep1<<<2176, blk, 0, stream>>>(W_qkv, W_o, Wq_c, Wk_c, Wv_c, W_co, WTqkv,
                                  WTo, WTqc, WTkc, WTvc, WTco, mem, memb);

  // --- self-attention block
  ln_kernel<<<4096, blk, 0, stream>>>(tgt, g1, be1, xb);
  gemm8p<3, 3><<<dim3(16, 16), blk512, 0, stream>>>(
      xb, WTqkv, b_qkv, qb, kb, vbT, 4096, 3072, 1024, 11, rc, rsn);
  attn_kernel<1><<<dim3(16, 32), blk512, 0, stream>>>(qb, kb, vbT, at, 2048);
  gemm_bt<1, 64><<<dim3(8, 64), blk, 0, stream>>>(at, WTo, b_o, tgt, res,
                                                  nullptr, nullptr, 4096, 1024,
                                                  1024, 0, 1.f, nullptr,
                                                  nullptr);
  // --- cross-attention block
  ln_kernel<<<4096, blk, 0, stream>>>(res, g2, be2, xb);
  gemm_bt<4, 64><<<dim3(8, 64), blk, 0, stream>>>(
      xb, WTqc, bq_c, nullptr, qb, nullptr, nullptr, 4096, 1024, 1024, 11, QSC,
      nullptr, nullptr);
  gemm_bt<6, 64><<<dim3(8, 2, 2), blk, 0, stream>>>(
      memb, WTkc, bk_c, bv_c, kc, WTvc, vcT, 128, 1024, 1024, 6, 1.f, nullptr,
      nullptr);
  attn_kernel<0><<<dim3(16, 32), blk512, 0, stream>>>(qb, kc, vcT, at, 64);
  gemm_bt<1, 64><<<dim3(8, 64), blk, 0, stream>>>(at, WTco, b_co, res, res,
                                                  nullptr, nullptr, 4096, 1024,
                                                  1024, 0, 1.f, nullptr,
                                                  nullptr);
  // --- FFN block
  prep2<<<2048, blk, 0, stream>>>(W1, W2, WT1, WT2);
  ln_kernel<<<4096, blk, 0, stream>>>(res, g3, be3, xb);
  gemm8p<2, 4><<<dim3(16, 16), blk512, 0, stream>>>(xb, WT1, b1, ffh, nullptr,
                                                    nullptr, 4096, 4096, 1024,
                                                    0, nullptr, nullptr);
  gemm_bt<1, 64><<<dim3(8, 64), blk, 0, stream>>>(ffh, WT2, b2, res, res,
                                                  nullptr, nullptr, 4096, 1024,
                                                  4096, 0, 1.f, nullptr,
                                                  nullptr);
}

// Round 6
// 469.328 us; speedup vs baseline: 1.0510x; 1.0510x over previous
//
#include <hip/hip_runtime.h>

typedef unsigned short u16;
typedef short bf16x8 __attribute__((ext_vector_type(8)));
typedef float f32x4 __attribute__((ext_vector_type(4)));

#define HN 16
#define SD 64
#define SEQ 2048
#define DM 1024
#define QSC 0.18033688f  // 0.125 * log2(e): softmax done in exp2 domain

__device__ __forceinline__ float bf2f(u16 h) {
  return __uint_as_float(((unsigned int)h) << 16);
}
__device__ __forceinline__ u16 f2bf(float f) {
  unsigned int x = __float_as_uint(f);
  x += 0x7fffu + ((x >> 16) & 1u);
  return (u16)(x >> 16);
}
__device__ __forceinline__ float geluf(float x) {
  return 0.5f * x * (1.0f + erff(x * 0.70710678118654752f));
}
__device__ __forceinline__ void load_lds16(const u16* g, u16* l) {
  __builtin_amdgcn_global_load_lds(
      (const __attribute__((address_space(1))) void*)g,
      (__attribute__((address_space(3))) void*)l, 16, 0, 0);
}
// LDS byte offset of a generic pointer known to point into LDS.
__device__ __forceinline__ unsigned ldsoff(const u16* p) {
  return (unsigned)(unsigned long long)(
      const __attribute__((address_space(3))) u16*)p;
}

// ----------------------------------------------------- transpose tile (dev)
__device__ __forceinline__ void trans_tile(const float* __restrict__ in,
                                           u16* __restrict__ out, int K, int N,
                                           int tx, int ty, int tid,
                                           u16 (*T)[72]) {
  const int n0 = tx * 64, k0 = ty * 64;
#pragma unroll
  for (int it = 0; it < 2; ++it) {
    const int t = it * 256 + tid, r = t >> 3, c = (t & 7) * 8;
    const float* src = &in[(size_t)(k0 + r) * N + n0 + c];
    float4 d0 = *(const float4*)src;
    float4 d1 = *(const float4*)(src + 4);
    T[r][c + 0] = f2bf(d0.x);
    T[r][c + 1] = f2bf(d0.y);
    T[r][c + 2] = f2bf(d0.z);
    T[r][c + 3] = f2bf(d0.w);
    T[r][c + 4] = f2bf(d1.x);
    T[r][c + 5] = f2bf(d1.y);
    T[r][c + 6] = f2bf(d1.z);
    T[r][c + 7] = f2bf(d1.w);
  }
  __syncthreads();
#pragma unroll
  for (int it = 0; it < 2; ++it) {
    const int t = it * 256 + tid, r = t >> 3, c = (t & 7) * 8;
    uint4 d;
    u16* p = (u16*)&d;
#pragma unroll
    for (int j = 0; j < 8; ++j) p[j] = T[c + j][r];
    *(uint4*)&out[(size_t)(n0 + r) * K + k0 + c] = d;
  }
}

// ------------------------------------------------- prep1: 6 WT + mem f2b
__global__ __launch_bounds__(256) void prep1(
    const float* __restrict__ Wqkv, const float* __restrict__ Wo,
    const float* __restrict__ Wqc, const float* __restrict__ Wkc,
    const float* __restrict__ Wvc, const float* __restrict__ Wco,
    u16* __restrict__ Tqkv, u16* __restrict__ To, u16* __restrict__ Tqc,
    u16* __restrict__ Tkc, u16* __restrict__ Tvc, u16* __restrict__ Tco,
    const float* __restrict__ mem, u16* __restrict__ memb) {
  __shared__ u16 T[64][72];
  const int t = blockIdx.x, tid = threadIdx.x;
  if (t < 768) {
    trans_tile(Wqkv, Tqkv, 1024, 3072, t % 48, t / 48, tid, T);
    return;
  }
  if (t < 2048) {
    const int u = t - 768, m = u >> 8, sub = u & 255;
    const float* in;
    u16* out;
    if (m == 0) { in = Wo; out = To; }
    else if (m == 1) { in = Wqc; out = Tqc; }
    else if (m == 2) { in = Wkc; out = Tkc; }
    else if (m == 3) { in = Wvc; out = Tvc; }
    else { in = Wco; out = Tco; }
    trans_tile(in, out, 1024, 1024, sub & 15, sub >> 4, tid, T);
    return;
  }
  const int i = ((t - 2048) * 256 + tid) * 4;
  float4 d = *(const float4*)&mem[i];
  uint2 o;
  u16* po = (u16*)&o;
  po[0] = f2bf(d.x);
  po[1] = f2bf(d.y);
  po[2] = f2bf(d.z);
  po[3] = f2bf(d.w);
  *(uint2*)&memb[i] = o;
}

// ------------------------------------------------- prep2: W1 + W2 transpose
__global__ __launch_bounds__(256) void prep2(const float* __restrict__ W1,
                                             const float* __restrict__ W2,
                                             u16* __restrict__ T1,
                                             u16* __restrict__ T2) {
  __shared__ u16 T[64][72];
  const int t = blockIdx.x, tid = threadIdx.x;
  if (t < 1024) {
    trans_tile(W1, T1, 1024, 4096, t & 63, t >> 6, tid, T);
  } else {
    const int u = t - 1024;
    trans_tile(W2, T2, 4096, 1024, u & 15, u >> 4, tid, T);
  }
}

// ---------------------------------------------------------------- layernorm
__global__ __launch_bounds__(256) void ln_kernel(
    const float* __restrict__ x, const float* __restrict__ g,
    const float* __restrict__ be, u16* __restrict__ y) {
  const int row = blockIdx.x, tid = threadIdx.x;
  const float* xr = x + (size_t)row * DM;
  float4 d = *(const float4*)&xr[tid * 4];
  float v[4] = {d.x, d.y, d.z, d.w};
  float s1 = 0.f, s2 = 0.f;
#pragma unroll
  for (int j = 0; j < 4; ++j) {
    s1 += v[j];
    s2 += v[j] * v[j];
  }
#pragma unroll
  for (int dd = 1; dd < 64; dd <<= 1) {
    s1 += __shfl_xor(s1, dd, 64);
    s2 += __shfl_xor(s2, dd, 64);
  }
  __shared__ float p1[4], p2[4];
  const int lane = tid & 63, wv = tid >> 6;
  if (lane == 0) {
    p1[wv] = s1;
    p2[wv] = s2;
  }
  __syncthreads();
  s1 = p1[0] + p1[1] + p1[2] + p1[3];
  s2 = p2[0] + p2[1] + p2[2] + p2[3];
  const float mu = s1 * (1.f / DM);
  const float rs = rsqrtf(fmaxf(s2 * (1.f / DM) - mu * mu, 0.f) + 1e-5f);
  float4 gg = *(const float4*)&g[tid * 4];
  float4 bb = *(const float4*)&be[tid * 4];
  const float gv[4] = {gg.x, gg.y, gg.z, gg.w};
  const float bv[4] = {bb.x, bb.y, bb.z, bb.w};
  uint2 o;
  u16* po = (u16*)&o;
#pragma unroll
  for (int j = 0; j < 4; ++j) po[j] = f2bf((v[j] - mu) * rs * gv[j] + bv[j]);
  *(uint2*)&y[(size_t)row * DM + tid * 4] = o;
}

// ---------------------------------------------------------------- GEMM (r13)
// TM x 128 tile, BK=64, 4 waves, DOUBLE-BUFFERED with ONE barrier per K-tile
// (T3-minimum recipe): STAGE(t+1 -> buf^1) issued FIRST, asm ds_read frags of
// buf, lgkmcnt(0)+sched_barrier, MFMA, vmcnt(0), barrier. Stage latency hides
// under reads+MFMA; LDS 48KB -> 2 blocks/CU for cross-block overlap.
template <int EPI, int TM>
__global__ __launch_bounds__(256) void gemm_bt(
    const u16* __restrict__ A, const u16* __restrict__ Bt,
    const float* __restrict__ bias, const float* __restrict__ resid,
    void* __restrict__ C0, u16* __restrict__ C1, u16* __restrict__ C2, int M,
    int N, int K, int rpbl, float sc, const float* __restrict__ rcos,
    const float* __restrict__ rsin) {
  constexpr int MI = TM / 32;
  __shared__ __align__(16) u16 As[2][TM][64];
  __shared__ __align__(16) u16 Bs[2][128][64];
  const int tid = threadIdx.x;
  const int lane = tid & 63, wv = tid >> 6;
  const int l16 = lane & 15, quad = lane >> 4;

  if (EPI == 6 && blockIdx.z) {
    Bt = (const u16*)C1;
    bias = resid;
  }

  int bx = blockIdx.x, by = blockIdx.y;
  const int gx = gridDim.x, gy = gridDim.y;
  if ((gy & 7) == 0) {
    const int f = by * gx + bx;
    const int c = f & 7, j = f >> 3;
    const int jm = j / gx;
    by = c * (gy >> 3) + jm;
    bx = j - jm * gx;
  }
  const int m0 = by * TM, n0 = bx * 128;
  const int wm = (wv >> 1) * (TM / 2), wn = (wv & 1) * 64;
  const int nk = K >> 6;

  const int srow = lane >> 3;
  const int sblk = (lane & 7) ^ srow;
  const u16* ag[MI];
  const u16* bg[4];
  u16* la[MI];
  u16* lb[4];
#pragma unroll
  for (int i = 0; i < MI; ++i) {
    const int r0 = i * 32 + wv * 8;
    ag[i] = A + (size_t)(m0 + r0 + srow) * K + sblk * 8;
    la[i] = &As[0][r0][0] + lane * 8;
  }
#pragma unroll
  for (int i = 0; i < 4; ++i) {
    const int r0 = i * 32 + wv * 8;
    bg[i] = Bt + (size_t)(n0 + r0 + srow) * K + sblk * 8;
    lb[i] = &Bs[0][r0][0] + lane * 8;
  }

  // fragment LDS byte addresses (buf0); buf adds literal imm in the asm.
  unsigned aad[2][MI], bad[2][4];
#pragma unroll
  for (int kk = 0; kk < 2; ++kk) {
#pragma unroll
    for (int mi = 0; mi < MI; ++mi) {
      const int row = wm + mi * 16 + l16;
      const int blk = (kk * 4 + quad) ^ (row & 7);
      aad[kk][mi] = ldsoff(&As[0][0][0]) + (unsigned)(row * 128 + blk * 16);
    }
#pragma unroll
    for (int ni = 0; ni < 4; ++ni) {
      const int row = wn + ni * 16 + l16;
      const int blk = (kk * 4 + quad) ^ (row & 7);
      bad[kk][ni] = ldsoff(&Bs[0][0][0]) + (unsigned)(row * 128 + blk * 16);
    }
  }

  f32x4 acc[MI][4] = {};

#define STB(P, ST)                                                            \
  {                                                                           \
    const int tt = (ST) < nk ? (ST) : nk - 1;                                 \
    const int k0s = tt << 6;                                                  \
    _Pragma("unroll") for (int i = 0; i < MI; ++i)                            \
        load_lds16(ag[i] + k0s, la[i] + (P) * (TM * 64));                     \
    _Pragma("unroll") for (int i = 0; i < 4; ++i)                             \
        load_lds16(bg[i] + k0s, lb[i] + (P) * 8192);                          \
  }

#define TILEB(CB, NP, ST)                                                     \
  {                                                                           \
    STB(NP, ST);                                                              \
    bf16x8 afr[2][MI], bfr[2][4];                                             \
    _Pragma("unroll") for (int kk = 0; kk < 2; ++kk) {                        \
      _Pragma("unroll") for (int mi = 0; mi < MI; ++mi)                       \
          asm volatile("ds_read_b128 %0, %1 offset:%2"                        \
                       : "=v"(afr[kk][mi])                                    \
                       : "v"(aad[kk][mi]), "i"((CB) * (TM * 128)));           \
      _Pragma("unroll") for (int ni = 0; ni < 4; ++ni)                        \
          asm volatile("ds_read_b128 %0, %1 offset:%2"                        \
                       : "=v"(bfr[kk][ni])                                    \
                       : "v"(bad[kk][ni]), "i"((CB)*16384));                  \
    }                                                                         \
    asm volatile("s_waitcnt lgkmcnt(0)");                                     \
    __builtin_amdgcn_sched_barrier(0);                                        \
    __builtin_amdgcn_s_setprio(1);                                            \
    _Pragma("unroll") for (int kk = 0; kk < 2; ++kk)                          \
        _Pragma("unroll") for (int mi = 0; mi < MI; ++mi)                     \
            _Pragma("unroll") for (int ni = 0; ni < 4; ++ni) acc[mi][ni] =    \
                __builtin_amdgcn_mfma_f32_16x16x32_bf16(                      \
                    afr[kk][mi], bfr[kk][ni], acc[mi][ni], 0, 0, 0);          \
    __builtin_amdgcn_s_setprio(0);                                            \
    asm volatile("s_waitcnt vmcnt(0)");                                       \
    __builtin_amdgcn_s_barrier();                                             \
  }

  STB(0, 0);
  asm volatile("s_waitcnt vmcnt(0)");
  __builtin_amdgcn_s_barrier();
  for (int t = 0; t < nk; t += 2) {  // nk even (16 or 64)
    TILEB(0, 1, t + 1)
    TILEB(1, 0, t + 2)
  }
#undef TILEB
#undef STB

  const int SL = 1 << rpbl;
#pragma unroll
  for (int mi = 0; mi < MI; ++mi) {
#pragma unroll
    for (int ni = 0; ni < 4; ++ni) {
#pragma unroll
      for (int r = 0; r < 4; ++r) {
        const int row = m0 + wm + mi * 16 + quad * 4 + r;
        const int col = n0 + wn + ni * 16 + l16;
        float vv = acc[mi][ni][r] + bias[col];
        if (EPI == 1) {
          vv += resid[(size_t)row * N + col];
          ((float*)C0)[(size_t)row * N + col] = vv;
        } else if (EPI == 2) {
          ((u16*)C0)[(size_t)row * N + col] = f2bf(geluf(vv));
        } else if (EPI == 3) {
          const float partner = __shfl_xor(vv, 1);
          const int which = col >> 10;
          const int nn = col & 1023;
          const int h = nn >> 6, hd = nn & 63;
          const int b = row >> rpbl;
          const int s = row & (SL - 1);
          if (which == 2) {
            C2[(((size_t)b * HN + h) * SD + hd) * SL + s] = f2bf(vv);
          } else {
            const int p = hd >> 1;
            const float cv = rcos[s * 32 + p];
            const float sv2 = rsin[s * 32 + p];
            float o = (hd & 1) ? (partner * sv2 + vv * cv)
                               : (vv * cv - partner * sv2);
            if (which == 0) o *= QSC;
            u16* dst = (which == 0) ? (u16*)C0 : C1;
            dst[(((size_t)b * HN + h) * SL + s) * SD + hd] = f2bf(o);
          }
        } else if (EPI == 4) {
          vv *= sc;
          const int h = col >> 6, hd = col & 63;
          const int b = row >> rpbl;
          const int s = row & (SL - 1);
          ((u16*)C0)[(((size_t)b * HN + h) * SL + s) * SD + hd] = f2bf(vv);
        } else if (EPI == 5) {
          const int h = col >> 6, hd = col & 63;
          const int b = row >> rpbl;
          const int s = row & (SL - 1);
          ((u16*)C0)[(((size_t)b * HN + h) * SD + hd) * SL + s] = f2bf(vv);
        } else if (EPI == 6) {
          const int h = col >> 6, hd = col & 63;
          const int b = row >> rpbl;
          const int s = row & (SL - 1);
          if (blockIdx.z == 0)
            ((u16*)C0)[(((size_t)b * HN + h) * SL + s) * SD + hd] = f2bf(vv);
          else
            C2[(((size_t)b * HN + h) * SD + hd) * SL + s] = f2bf(vv);
        } else {
          ((u16*)C0)[(size_t)row * N + col] = f2bf(vv);
        }
      }
    }
  }
}

// ---------------------------------------------------------------- GEMM 8p
// r13: 256 x (NI*64) tile, 8 waves, ONE phase per K-tile: STAGE(t+1) first,
// then kk0 {reads, lgkm0, MFMA}, kk1 {reads, lgkm0, MFMA}, one vmcnt(0), one
// barrier. For NI=3, waves 6-7 skip B staging (rows 192..255 unused).
template <int EPI, int NI>
__global__ __launch_bounds__(512, 2) void gemm8p(
    const u16* __restrict__ A, const u16* __restrict__ Bt,
    const float* __restrict__ bias, void* __restrict__ C0,
    u16* __restrict__ C1, u16* __restrict__ C2, int M, int N, int K, int rpbl,
    const float* __restrict__ rcos, const float* __restrict__ rsin) {
  __shared__ __align__(16) u16 L[4][2][8192];  // [A0,A1,B0,B1][buf][128x64]
  const int tid = threadIdx.x;
  const int lane = tid & 63, wv = tid >> 6;
  const int l16 = lane & 15, quad = lane >> 4;
  int bx = blockIdx.x, by = blockIdx.y;
  {  // bijective XCD chunk swizzle (nwg % 8 == 0 for all our grids)
    const int gx = gridDim.x;
    const int nwg = gx * gridDim.y;
    if ((nwg & 7) == 0) {
      const int f = by * gx + bx;
      const int q = nwg >> 3;
      const int wg = (f & 7) * q + (f >> 3);
      by = wg / gx;
      bx = wg - by * gx;
    }
  }
  const int m0 = by * 256, n0 = bx * (NI * 64);
  const int wm = (wv >> 2) * 128, wn = (wv & 3) * (NI * 16);
  const int nk = K >> 6;

  const u16* Ag = A + (size_t)m0 * K;
  const u16* Bg = Bt + (size_t)n0 * K;

#define STAGE(MAT, H, ST, P)                                                  \
  if ((MAT) == 0 || wv < 2 * NI) {                                            \
    const int tt = (ST) < nk ? (ST) : nk - 1; /* clamp: dummy loads */        \
    const int k0s = tt << 6;                                                  \
    u16* dst = &L[(MAT)*2 + (H)][P][0];                                       \
    const u16* srcp = (MAT) ? Bg : Ag;                                        \
    _Pragma("unroll") for (int j = 0; j < 2; ++j) {                           \
      const int li = wv * 2 + j;                                              \
      const int pr = li * 8 + (lane >> 3);                                    \
      const int bb = lane & 7;                                                \
      const int gg2 = bb ^ (pr & 7);                                          \
      const int rw = 2 * pr + (gg2 >> 2);                                     \
      load_lds16(srcp + (size_t)rw * K + k0s + (H)*32 + (gg2 & 3) * 8,        \
                 dst + li * 512 + lane * 8);                                  \
    }                                                                         \
  }

  // per-thread LDS byte addresses (buf0, kk0); KK/CB add immediates:
  // A(kk,cb) at (kk*2+cb)*16384; B at 65536 + same.
  unsigned aaddr[2][4], baddr[NI];
  {
    const unsigned Lb = ldsoff(&L[0][0][0]);
#pragma unroll
    for (int MH = 0; MH < 2; ++MH)
#pragma unroll
      for (int mi = 0; mi < 4; ++mi) {
        const int R = wm + MH * 64 + mi * 16 + l16;
        const int p = R >> 1, g = (R & 1) * 4 + quad, b = g ^ (p & 7);
        aaddr[MH][mi] = Lb + (unsigned)(p * 64 + b * 8) * 2u;
      }
#pragma unroll
    for (int ni = 0; ni < NI; ++ni) {
      const int R = wn + ni * 16 + l16;
      const int p = R >> 1, g = (R & 1) * 4 + quad, b = g ^ (p & 7);
      baddr[ni] = Lb + 65536u + (unsigned)(p * 64 + b * 8) * 2u;
    }
  }

  f32x4 acc[8][NI] = {};

// half-tile compute for (CB,KK): reads + lgkm0 + MFMA. No barriers inside.
#define HALF(CB, KK)                                                          \
  {                                                                           \
    bf16x8 af[2][4];                                                          \
    bf16x8 bfr[NI];                                                           \
    _Pragma("unroll") for (int mh = 0; mh < 2; ++mh)                          \
        _Pragma("unroll") for (int mi = 0; mi < 4; ++mi)                      \
            asm volatile("ds_read_b128 %0, %1 offset:%2"                      \
                         : "=v"(af[mh][mi])                                   \
                         : "v"(aaddr[mh][mi]),                                \
                           "i"((KK)*32768 + (CB)*16384));                     \
    _Pragma("unroll") for (int ni = 0; ni < NI; ++ni)                         \
        asm volatile("ds_read_b128 %0, %1 offset:%2"                          \
                     : "=v"(bfr[ni])                                          \
                     : "v"(baddr[ni]), "i"((KK)*32768 + (CB)*16384));         \
    asm volatile("s_waitcnt lgkmcnt(0)");                                     \
    __builtin_amdgcn_sched_barrier(0);                                        \
    __builtin_amdgcn_s_setprio(1);                                            \
    _Pragma("unroll") for (int mh = 0; mh < 2; ++mh)                          \
        _Pragma("unroll") for (int mi = 0; mi < 4; ++mi)                      \
            _Pragma("unroll") for (int ni = 0; ni < NI; ++ni)                 \
                acc[mh * 4 + mi][ni] =                                        \
                    __builtin_amdgcn_mfma_f32_16x16x32_bf16(                  \
                        af[mh][mi], bfr[ni], acc[mh * 4 + mi][ni], 0, 0, 0);  \
    __builtin_amdgcn_s_setprio(0);                                            \
  }

#define TILE8(CB, NP, ST)                                                     \
  {                                                                           \
    STAGE(0, 0, ST, NP);                                                      \
    STAGE(1, 0, ST, NP);                                                      \
    STAGE(0, 1, ST, NP);                                                      \
    STAGE(1, 1, ST, NP);                                                      \
    HALF(CB, 0)                                                               \
    HALF(CB, 1)                                                               \
    asm volatile("s_waitcnt vmcnt(0)");                                       \
    __builtin_amdgcn_s_barrier();                                             \
  }

  // prologue: tile 0 -> buf0
  STAGE(0, 0, 0, 0);
  STAGE(1, 0, 0, 0);
  STAGE(0, 1, 0, 0);
  STAGE(1, 1, 0, 0);
  asm volatile("s_waitcnt vmcnt(0)");
  __builtin_amdgcn_s_barrier();

  for (int t = 0; t < nk; t += 2) {  // nk even for all our shapes
    TILE8(0, 1, t + 1)
    TILE8(1, 0, t + 2)
  }
#undef TILE8
#undef HALF
#undef STAGE

  const int SL = 1 << rpbl;
#pragma unroll
  for (int mi = 0; mi < 8; ++mi) {
#pragma unroll
    for (int ni = 0; ni < NI; ++ni) {
#pragma unroll
      for (int r = 0; r < 4; ++r) {
        const int row = m0 + wm + mi * 16 + quad * 4 + r;
        const int col = n0 + wn + ni * 16 + l16;
        float vv = acc[mi][ni][r] + bias[col];
        if (EPI == 2) {
          ((u16*)C0)[(size_t)row * N + col] = f2bf(geluf(vv));
        } else if (EPI == 3) {
          const float partner = __shfl_xor(vv, 1);
          const int which = col >> 10;
          const int nn = col & 1023;
          const int h = nn >> 6, hd = nn & 63;
          const int b = row >> rpbl;
          const int s = row & (SL - 1);
          if (which == 2) {
            C2[(((size_t)b * HN + h) * SD + hd) * SL + s] = f2bf(vv);
          } else {
            const int p = hd >> 1;
            const float cv = rcos[s * 32 + p];
            const float sv2 = rsin[s * 32 + p];
            float o = (hd & 1) ? (partner * sv2 + vv * cv)
                               : (vv * cv - partner * sv2);
            if (which == 0) o *= QSC;
            u16* dst = (which == 0) ? (u16*)C0 : C1;
            dst[(((size_t)b * HN + h) * SL + s) * SD + hd] = f2bf(o);
          }
        } else {
          ((u16*)C0)[(size_t)row * N + col] = f2bf(vv);
        }
      }
    }
  }
}

// ---------------------------------------------------------------- attention
template <int CAUSAL>
__global__ __launch_bounds__(512, 4) void attn_kernel(
    const u16* __restrict__ q, const u16* __restrict__ k,
    const u16* __restrict__ vt, u16* __restrict__ out, int kv_len) {
  __shared__ u16 Qs[128][72], Ks[64][72], VTs[64][72];
  __shared__ u16 Ps[128][68];
  const int tid = threadIdx.x;
  const int lane = tid & 63, wv = tid >> 6;
  const int t2 = wv >> 2, w4 = wv & 3;
  const int l16 = lane & 15, quad = lane >> 4;
  const int bx = blockIdx.x, bh = blockIdx.y;
  const int qtA = bx;
  const int qtB = CAUSAL ? (31 - bx) : (bx + 16);
  const int qt = t2 ? qtB : qtA;
  const u16* qb = q + (size_t)bh * SEQ * SD;
  const u16* kb = k + (size_t)bh * kv_len * SD;
  const u16* vtb = vt + (size_t)bh * SD * kv_len;

#pragma unroll
  for (int it = 0; it < 2; ++it) {
    const int t = it * 512 + tid, r = t >> 3, c = (t & 7) * 8;
    const int qrow = (r < 64) ? (qtA * 64 + r) : (qtB * 64 + (r - 64));
    *(uint4*)&Qs[r][c] = *(const uint4*)&qb[(size_t)qrow * SD + c];
  }

  f32x4 o_acc[4] = {};
  float l_i[4] = {};

  const int ktiles = CAUSAL ? (qtB + 1) : ((kv_len + 63) >> 6);
  const int sr = tid >> 3, sc8 = (tid & 7) * 8;

  for (int kt = 0; kt < ktiles; ++kt) {
    const uint4 kd = *(const uint4*)&kb[((size_t)kt * 64 + sr) * SD + sc8];
    const uint4 vd = *(const uint4*)&vtb[(size_t)sr * kv_len + kt * 64 + sc8];
    __syncthreads();
    *(uint4*)&Ks[sr][sc8] = kd;
    *(uint4*)&VTs[sr][sc8] = vd;
    __syncthreads();

    if (kt <= qt) {
      const int roff = t2 * 64 + w4 * 16;
      f32x4 s_acc[4] = {};
#pragma unroll
      for (int kk = 0; kk < 64; kk += 32) {
        const bf16x8 aq = *(const bf16x8*)&Qs[roff + l16][kk + quad * 8];
#pragma unroll
        for (int ni = 0; ni < 4; ++ni) {
          const bf16x8 bk = *(const bf16x8*)&Ks[ni * 16 + l16][kk + quad * 8];
          s_acc[ni] = __builtin_amdgcn_mfma_f32_16x16x32_bf16(aq, bk, s_acc[ni],
                                                              0, 0, 0);
        }
      }
      float rsum[4] = {0.f, 0.f, 0.f, 0.f};
      const bool dg = CAUSAL && (kt == qt);
#pragma unroll
      for (int ni = 0; ni < 4; ++ni)
#pragma unroll
        for (int r = 0; r < 4; ++r) {
          float sv = s_acc[ni][r];
          if (dg && (ni * 16 + l16 > w4 * 16 + quad * 4 + r)) sv = -1e9f;
          const float pe = __builtin_amdgcn_exp2f(sv);
          rsum[r] += pe;
          Ps[wv * 16 + quad * 4 + r][ni * 16 + l16] =
              (u16)(__float_as_uint(pe) >> 16);
        }
#pragma unroll
      for (int r = 0; r < 4; ++r) {
#pragma unroll
        for (int dd = 1; dd < 16; dd <<= 1)
          rsum[r] += __shfl_xor(rsum[r], dd, 64);
        l_i[r] += rsum[r];
      }
#pragma unroll
      for (int kk = 0; kk < 64; kk += 32) {
        const bf16x8 ap = *(const bf16x8*)&Ps[wv * 16 + l16][kk + quad * 8];
#pragma unroll
        for (int ni = 0; ni < 4; ++ni) {
          const bf16x8 bv = *(const bf16x8*)&VTs[ni * 16 + l16][kk + quad * 8];
          o_acc[ni] = __builtin_amdgcn_mfma_f32_16x16x32_bf16(ap, bv, o_acc[ni],
                                                              0, 0, 0);
        }
      }
    }
  }

  const int b = bh >> 4, h = bh & 15;
#pragma unroll
  for (int r = 0; r < 4; ++r) {
    const float inv = 1.f / l_i[r];
    const int s = qt * 64 + w4 * 16 + quad * 4 + r;
#pragma unroll
    for (int ni = 0; ni < 4; ++ni)
      out[((size_t)b * SEQ + s) * DM + h * SD + ni * 16 + l16] =
          f2bf(o_acc[ni][r] * inv);
  }
}

// ---------------------------------------------------------------- launch
extern "C" void kernel_launch(void* const* d_in, const int* in_sizes, int n_in,
                              void* d_out, int out_size, void* d_ws,
                              size_t ws_size, hipStream_t stream) {
  (void)in_sizes;
  (void)n_in;
  (void)out_size;
  (void)ws_size;
  const float* tgt = (const float*)d_in[0];
  const float* mem = (const float*)d_in[1];
  const float* rc = (const float*)d_in[2];
  const float* rsn = (const float*)d_in[3];
  const float* W_qkv = (const float*)d_in[4];
  const float* b_qkv = (const float*)d_in[5];
  const float* W_o = (const float*)d_in[6];
  const float* b_o = (const float*)d_in[7];
  const float* Wq_c = (const float*)d_in[8];
  const float* bq_c = (const float*)d_in[9];
  const float* Wk_c = (const float*)d_in[10];
  const float* bk_c = (const float*)d_in[11];
  const float* Wv_c = (const float*)d_in[12];
  const float* bv_c = (const float*)d_in[13];
  const float* W_co = (const float*)d_in[14];
  const float* b_co = (const float*)d_in[15];
  const float* W1 = (const float*)d_in[16];
  const float* b1 = (const float*)d_in[17];
  const float* W2 = (const float*)d_in[18];
  const float* b2 = (const float*)d_in[19];
  const float* g1 = (const float*)d_in[20];
  const float* be1 = (const float*)d_in[21];
  const float* g2 = (const float*)d_in[22];
  const float* be2 = (const float*)d_in[23];
  const float* g3 = (const float*)d_in[24];
  const float* be3 = (const float*)d_in[25];

  const size_t M1 = 1048576;
  u16* w = (u16*)d_ws;
  u16* WTqkv = w;
  u16* WTo = w + 3 * M1;
  u16* WTqc = w + 4 * M1;
  u16* WTkc = w + 5 * M1;
  u16* WTvc = w + 6 * M1;
  u16* WTco = w + 7 * M1;
  u16* WT1 = w;
  u16* WT2 = w + 4 * M1;
  u16* xb = w + 8 * M1;
  u16* qb = w + 12 * M1;
  u16* kb = w + 16 * M1;
  u16* vbT = w + 20 * M1;
  u16* at = w + 24 * M1;
  u16* kc = w + 28 * M1;
  u16* vcT = kc + 131072;
  u16* memb = vcT + 131072;
  u16* ffh = qb;
  float* res = (float*)d_out;

  dim3 blk(256), blk512(512);
  prep1<<<2176, blk, 0, stream>>>(W_qkv, W_o, Wq_c, Wk_c, Wv_c, W_co, WTqkv,
                                  WTo, WTqc, WTkc, WTvc, WTco, mem, memb);

  // --- self-attention block
  ln_kernel<<<4096, blk, 0, stream>>>(tgt, g1, be1, xb);
  gemm8p<3, 3><<<dim3(16, 16), blk512, 0, stream>>>(
      xb, WTqkv, b_qkv, qb, kb, vbT, 4096, 3072, 1024, 11, rc, rsn);
  attn_kernel<1><<<dim3(16, 32), blk512, 0, stream>>>(qb, kb, vbT, at, 2048);
  gemm_bt<1, 64><<<dim3(8, 64), blk, 0, stream>>>(at, WTo, b_o, tgt, res,
                                                  nullptr, nullptr, 4096, 1024,
                                                  1024, 0, 1.f, nullptr,
                                                  nullptr);
  // --- cross-attention block
  ln_kernel<<<4096, blk, 0, stream>>>(res, g2, be2, xb);
  gemm_bt<4, 64><<<dim3(8, 64), blk, 0, stream>>>(
      xb, WTqc, bq_c, nullptr, qb, nullptr, nullptr, 4096, 1024, 1024, 11, QSC,
      nullptr, nullptr);
  gemm_bt<6, 64><<<dim3(8, 2, 2), blk, 0, stream>>>(
      memb, WTkc, bk_c, bv_c, kc, WTvc, vcT, 128, 1024, 1024, 6, 1.f, nullptr,
      nullptr);
  attn_kernel<0><<<dim3(16, 32), blk512, 0, stream>>>(qb, kc, vcT, at, 64);
  gemm_bt<1, 64><<<dim3(8, 64), blk, 0, stream>>>(at, WTco, b_co, res, res,
                                                  nullptr, nullptr, 4096, 1024,
                                                  1024, 0, 1.f, nullptr,
                                                  nullptr);
  // --- FFN block
  prep2<<<2048, blk, 0, stream>>>(W1, W2, WT1, WT2);
  ln_kernel<<<4096, blk, 0, stream>>>(res, g3, be3, xb);
  gemm8p<2, 4><<<dim3(16, 16), blk512, 0, stream>>>(xb, WT1, b1, ffh, nullptr,
                                                    nullptr, 4096, 4096, 1024,
                                                    0, nullptr, nullptr);
  gemm_bt<1, 64><<<dim3(8, 64), blk, 0, stream>>>(ffh, WT2, b2, res, res,
                                                  nullptr, nullptr, 4096, 1024,
                                                  4096, 0, 1.f, nullptr,
                                                  nullptr);
}

// Round 7
// 459.054 us; speedup vs baseline: 1.0746x; 1.0224x over previous
//
#include <hip/hip_runtime.h>

typedef unsigned short u16;
typedef short bf16x8 __attribute__((ext_vector_type(8)));
typedef float f32x4 __attribute__((ext_vector_type(4)));

#define HN 16
#define SD 64
#define SEQ 2048
#define DM 1024
#define QSC 0.18033688f  // 0.125 * log2(e): softmax done in exp2 domain

__device__ __forceinline__ float bf2f(u16 h) {
  return __uint_as_float(((unsigned int)h) << 16);
}
__device__ __forceinline__ u16 f2bf(float f) {
  unsigned int x = __float_as_uint(f);
  x += 0x7fffu + ((x >> 16) & 1u);
  return (u16)(x >> 16);
}
__device__ __forceinline__ float geluf(float x) {
  return 0.5f * x * (1.0f + erff(x * 0.70710678118654752f));
}
__device__ __forceinline__ void load_lds16(const u16* g, u16* l) {
  __builtin_amdgcn_global_load_lds(
      (const __attribute__((address_space(1))) void*)g,
      (__attribute__((address_space(3))) void*)l, 16, 0, 0);
}
// LDS byte offset of a generic pointer known to point into LDS.
__device__ __forceinline__ unsigned ldsoff(const u16* p) {
  return (unsigned)(unsigned long long)(
      const __attribute__((address_space(3))) u16*)p;
}

// ----------------------------------------------------- transpose tile (dev)
__device__ __forceinline__ void trans_tile(const float* __restrict__ in,
                                           u16* __restrict__ out, int K, int N,
                                           int tx, int ty, int tid,
                                           u16 (*T)[72]) {
  const int n0 = tx * 64, k0 = ty * 64;
#pragma unroll
  for (int it = 0; it < 2; ++it) {
    const int t = it * 256 + tid, r = t >> 3, c = (t & 7) * 8;
    const float* src = &in[(size_t)(k0 + r) * N + n0 + c];
    float4 d0 = *(const float4*)src;
    float4 d1 = *(const float4*)(src + 4);
    T[r][c + 0] = f2bf(d0.x);
    T[r][c + 1] = f2bf(d0.y);
    T[r][c + 2] = f2bf(d0.z);
    T[r][c + 3] = f2bf(d0.w);
    T[r][c + 4] = f2bf(d1.x);
    T[r][c + 5] = f2bf(d1.y);
    T[r][c + 6] = f2bf(d1.z);
    T[r][c + 7] = f2bf(d1.w);
  }
  __syncthreads();
#pragma unroll
  for (int it = 0; it < 2; ++it) {
    const int t = it * 256 + tid, r = t >> 3, c = (t & 7) * 8;
    uint4 d;
    u16* p = (u16*)&d;
#pragma unroll
    for (int j = 0; j < 8; ++j) p[j] = T[c + j][r];
    *(uint4*)&out[(size_t)(n0 + r) * K + k0 + c] = d;
  }
}

// ------------------------------------------------- prep1: 6 WT + mem f2b
__global__ __launch_bounds__(256) void prep1(
    const float* __restrict__ Wqkv, const float* __restrict__ Wo,
    const float* __restrict__ Wqc, const float* __restrict__ Wkc,
    const float* __restrict__ Wvc, const float* __restrict__ Wco,
    u16* __restrict__ Tqkv, u16* __restrict__ To, u16* __restrict__ Tqc,
    u16* __restrict__ Tkc, u16* __restrict__ Tvc, u16* __restrict__ Tco,
    const float* __restrict__ mem, u16* __restrict__ memb) {
  __shared__ u16 T[64][72];
  const int t = blockIdx.x, tid = threadIdx.x;
  if (t < 768) {
    trans_tile(Wqkv, Tqkv, 1024, 3072, t % 48, t / 48, tid, T);
    return;
  }
  if (t < 2048) {
    const int u = t - 768, m = u >> 8, sub = u & 255;
    const float* in;
    u16* out;
    if (m == 0) { in = Wo; out = To; }
    else if (m == 1) { in = Wqc; out = Tqc; }
    else if (m == 2) { in = Wkc; out = Tkc; }
    else if (m == 3) { in = Wvc; out = Tvc; }
    else { in = Wco; out = Tco; }
    trans_tile(in, out, 1024, 1024, sub & 15, sub >> 4, tid, T);
    return;
  }
  const int i = ((t - 2048) * 256 + tid) * 4;
  float4 d = *(const float4*)&mem[i];
  uint2 o;
  u16* po = (u16*)&o;
  po[0] = f2bf(d.x);
  po[1] = f2bf(d.y);
  po[2] = f2bf(d.z);
  po[3] = f2bf(d.w);
  *(uint2*)&memb[i] = o;
}

// ------------------------------------------------- prep2: W1 + W2 transpose
__global__ __launch_bounds__(256) void prep2(const float* __restrict__ W1,
                                             const float* __restrict__ W2,
                                             u16* __restrict__ T1,
                                             u16* __restrict__ T2) {
  __shared__ u16 T[64][72];
  const int t = blockIdx.x, tid = threadIdx.x;
  if (t < 1024) {
    trans_tile(W1, T1, 1024, 4096, t & 63, t >> 6, tid, T);
  } else {
    const int u = t - 1024;
    trans_tile(W2, T2, 4096, 1024, u & 15, u >> 4, tid, T);
  }
}

// ---------------------------------------------------------------- layernorm
__global__ __launch_bounds__(256) void ln_kernel(
    const float* __restrict__ x, const float* __restrict__ g,
    const float* __restrict__ be, u16* __restrict__ y) {
  const int row = blockIdx.x, tid = threadIdx.x;
  const float* xr = x + (size_t)row * DM;
  float4 d = *(const float4*)&xr[tid * 4];
  float v[4] = {d.x, d.y, d.z, d.w};
  float s1 = 0.f, s2 = 0.f;
#pragma unroll
  for (int j = 0; j < 4; ++j) {
    s1 += v[j];
    s2 += v[j] * v[j];
  }
#pragma unroll
  for (int dd = 1; dd < 64; dd <<= 1) {
    s1 += __shfl_xor(s1, dd, 64);
    s2 += __shfl_xor(s2, dd, 64);
  }
  __shared__ float p1[4], p2[4];
  const int lane = tid & 63, wv = tid >> 6;
  if (lane == 0) {
    p1[wv] = s1;
    p2[wv] = s2;
  }
  __syncthreads();
  s1 = p1[0] + p1[1] + p1[2] + p1[3];
  s2 = p2[0] + p2[1] + p2[2] + p2[3];
  const float mu = s1 * (1.f / DM);
  const float rs = rsqrtf(fmaxf(s2 * (1.f / DM) - mu * mu, 0.f) + 1e-5f);
  float4 gg = *(const float4*)&g[tid * 4];
  float4 bb = *(const float4*)&be[tid * 4];
  const float gv[4] = {gg.x, gg.y, gg.z, gg.w};
  const float bv[4] = {bb.x, bb.y, bb.z, bb.w};
  uint2 o;
  u16* po = (u16*)&o;
#pragma unroll
  for (int j = 0; j < 4; ++j) po[j] = f2bf((v[j] - mu) * rs * gv[j] + bv[j]);
  *(uint2*)&y[(size_t)row * DM + tid * 4] = o;
}

// ---------------------------------------------------------------- GEMM (r13)
// TM x 128 tile, BK=64, 4 waves, DOUBLE-BUFFERED with ONE barrier per K-tile
// (T3-minimum recipe): STAGE(t+1 -> buf^1) issued FIRST, asm ds_read frags of
// buf, lgkmcnt(0)+sched_barrier, MFMA, vmcnt(0), barrier. Stage latency hides
// under reads+MFMA; LDS 48KB -> 2 blocks/CU for cross-block overlap.
template <int EPI, int TM>
__global__ __launch_bounds__(256) void gemm_bt(
    const u16* __restrict__ A, const u16* __restrict__ Bt,
    const float* __restrict__ bias, const float* __restrict__ resid,
    void* __restrict__ C0, u16* __restrict__ C1, u16* __restrict__ C2, int M,
    int N, int K, int rpbl, float sc, const float* __restrict__ rcos,
    const float* __restrict__ rsin) {
  constexpr int MI = TM / 32;
  __shared__ __align__(16) u16 As[2][TM][64];
  __shared__ __align__(16) u16 Bs[2][128][64];
  const int tid = threadIdx.x;
  const int lane = tid & 63, wv = tid >> 6;
  const int l16 = lane & 15, quad = lane >> 4;

  if (EPI == 6 && blockIdx.z) {
    Bt = (const u16*)C1;
    bias = resid;
  }

  int bx = blockIdx.x, by = blockIdx.y;
  const int gx = gridDim.x, gy = gridDim.y;
  if ((gy & 7) == 0) {
    const int f = by * gx + bx;
    const int c = f & 7, j = f >> 3;
    const int jm = j / gx;
    by = c * (gy >> 3) + jm;
    bx = j - jm * gx;
  }
  const int m0 = by * TM, n0 = bx * 128;
  const int wm = (wv >> 1) * (TM / 2), wn = (wv & 1) * 64;
  const int nk = K >> 6;

  const int srow = lane >> 3;
  const int sblk = (lane & 7) ^ srow;
  const u16* ag[MI];
  const u16* bg[4];
  u16* la[MI];
  u16* lb[4];
#pragma unroll
  for (int i = 0; i < MI; ++i) {
    const int r0 = i * 32 + wv * 8;
    ag[i] = A + (size_t)(m0 + r0 + srow) * K + sblk * 8;
    la[i] = &As[0][r0][0] + lane * 8;
  }
#pragma unroll
  for (int i = 0; i < 4; ++i) {
    const int r0 = i * 32 + wv * 8;
    bg[i] = Bt + (size_t)(n0 + r0 + srow) * K + sblk * 8;
    lb[i] = &Bs[0][r0][0] + lane * 8;
  }

  // fragment LDS byte addresses (buf0); buf adds literal imm in the asm.
  unsigned aad[2][MI], bad[2][4];
#pragma unroll
  for (int kk = 0; kk < 2; ++kk) {
#pragma unroll
    for (int mi = 0; mi < MI; ++mi) {
      const int row = wm + mi * 16 + l16;
      const int blk = (kk * 4 + quad) ^ (row & 7);
      aad[kk][mi] = ldsoff(&As[0][0][0]) + (unsigned)(row * 128 + blk * 16);
    }
#pragma unroll
    for (int ni = 0; ni < 4; ++ni) {
      const int row = wn + ni * 16 + l16;
      const int blk = (kk * 4 + quad) ^ (row & 7);
      bad[kk][ni] = ldsoff(&Bs[0][0][0]) + (unsigned)(row * 128 + blk * 16);
    }
  }

  f32x4 acc[MI][4] = {};

#define STB(P, ST)                                                            \
  {                                                                           \
    const int tt = (ST) < nk ? (ST) : nk - 1;                                 \
    const int k0s = tt << 6;                                                  \
    _Pragma("unroll") for (int i = 0; i < MI; ++i)                            \
        load_lds16(ag[i] + k0s, la[i] + (P) * (TM * 64));                     \
    _Pragma("unroll") for (int i = 0; i < 4; ++i)                             \
        load_lds16(bg[i] + k0s, lb[i] + (P) * 8192);                          \
  }

#define TILEB(CB, NP, ST)                                                     \
  {                                                                           \
    STB(NP, ST);                                                              \
    bf16x8 afr[2][MI], bfr[2][4];                                             \
    _Pragma("unroll") for (int kk = 0; kk < 2; ++kk) {                        \
      _Pragma("unroll") for (int mi = 0; mi < MI; ++mi)                       \
          asm volatile("ds_read_b128 %0, %1 offset:%2"                        \
                       : "=v"(afr[kk][mi])                                    \
                       : "v"(aad[kk][mi]), "i"((CB) * (TM * 128)));           \
      _Pragma("unroll") for (int ni = 0; ni < 4; ++ni)                        \
          asm volatile("ds_read_b128 %0, %1 offset:%2"                        \
                       : "=v"(bfr[kk][ni])                                    \
                       : "v"(bad[kk][ni]), "i"((CB)*16384));                  \
    }                                                                         \
    asm volatile("s_waitcnt lgkmcnt(0)");                                     \
    __builtin_amdgcn_sched_barrier(0);                                        \
    __builtin_amdgcn_s_setprio(1);                                            \
    _Pragma("unroll") for (int kk = 0; kk < 2; ++kk)                          \
        _Pragma("unroll") for (int mi = 0; mi < MI; ++mi)                     \
            _Pragma("unroll") for (int ni = 0; ni < 4; ++ni) acc[mi][ni] =    \
                __builtin_amdgcn_mfma_f32_16x16x32_bf16(                      \
                    afr[kk][mi], bfr[kk][ni], acc[mi][ni], 0, 0, 0);          \
    __builtin_amdgcn_s_setprio(0);                                            \
    asm volatile("s_waitcnt vmcnt(0)");                                       \
    __builtin_amdgcn_s_barrier();                                             \
  }

  STB(0, 0);
  asm volatile("s_waitcnt vmcnt(0)");
  __builtin_amdgcn_s_barrier();
  for (int t = 0; t < nk; t += 2) {  // nk even (16 or 64)
    TILEB(0, 1, t + 1)
    TILEB(1, 0, t + 2)
  }
#undef TILEB
#undef STB

  const int SL = 1 << rpbl;
#pragma unroll
  for (int mi = 0; mi < MI; ++mi) {
#pragma unroll
    for (int ni = 0; ni < 4; ++ni) {
#pragma unroll
      for (int r = 0; r < 4; ++r) {
        const int row = m0 + wm + mi * 16 + quad * 4 + r;
        const int col = n0 + wn + ni * 16 + l16;
        float vv = acc[mi][ni][r] + bias[col];
        if (EPI == 1) {
          vv += resid[(size_t)row * N + col];
          ((float*)C0)[(size_t)row * N + col] = vv;
        } else if (EPI == 2) {
          ((u16*)C0)[(size_t)row * N + col] = f2bf(geluf(vv));
        } else if (EPI == 3) {
          const float partner = __shfl_xor(vv, 1);
          const int which = col >> 10;
          const int nn = col & 1023;
          const int h = nn >> 6, hd = nn & 63;
          const int b = row >> rpbl;
          const int s = row & (SL - 1);
          if (which == 2) {
            C2[(((size_t)b * HN + h) * SD + hd) * SL + s] = f2bf(vv);
          } else {
            const int p = hd >> 1;
            const float cv = rcos[s * 32 + p];
            const float sv2 = rsin[s * 32 + p];
            float o = (hd & 1) ? (partner * sv2 + vv * cv)
                               : (vv * cv - partner * sv2);
            if (which == 0) o *= QSC;
            u16* dst = (which == 0) ? (u16*)C0 : C1;
            dst[(((size_t)b * HN + h) * SL + s) * SD + hd] = f2bf(o);
          }
        } else if (EPI == 4) {
          vv *= sc;
          const int h = col >> 6, hd = col & 63;
          const int b = row >> rpbl;
          const int s = row & (SL - 1);
          ((u16*)C0)[(((size_t)b * HN + h) * SL + s) * SD + hd] = f2bf(vv);
        } else if (EPI == 5) {
          const int h = col >> 6, hd = col & 63;
          const int b = row >> rpbl;
          const int s = row & (SL - 1);
          ((u16*)C0)[(((size_t)b * HN + h) * SD + hd) * SL + s] = f2bf(vv);
        } else if (EPI == 6) {
          const int h = col >> 6, hd = col & 63;
          const int b = row >> rpbl;
          const int s = row & (SL - 1);
          if (blockIdx.z == 0)
            ((u16*)C0)[(((size_t)b * HN + h) * SL + s) * SD + hd] = f2bf(vv);
          else
            C2[(((size_t)b * HN + h) * SD + hd) * SL + s] = f2bf(vv);
        } else {
          ((u16*)C0)[(size_t)row * N + col] = f2bf(vv);
        }
      }
    }
  }
}

// ---------------------------------------------------------------- GEMM 8p
// r14 = r12-exact gemm8p (best measured: <=62us): 256 x (NI*64) tile, BK=64,
// 8 waves, 512 thr, 1 block/CU. TWO fat phases per K-tile, each = 12
// ds_read_b128 + 2 half-tile stages + MFMA + COUNTED vmcnt(8) + 2 barriers.
// r13's 1-phase/vmcnt(0) variant regressed to 73us (m218: counted vmcnt IS
// the gain); NI=3 B-stage wave-skip removed (unsafe with per-wave counted
// vmcnt: skipping waves under-count and cross the barrier unretired).
template <int EPI, int NI>
__global__ __launch_bounds__(512, 2) void gemm8p(
    const u16* __restrict__ A, const u16* __restrict__ Bt,
    const float* __restrict__ bias, void* __restrict__ C0,
    u16* __restrict__ C1, u16* __restrict__ C2, int M, int N, int K, int rpbl,
    const float* __restrict__ rcos, const float* __restrict__ rsin) {
  __shared__ __align__(16) u16 L[4][2][8192];  // [A0,A1,B0,B1][buf][128x64]
  const int tid = threadIdx.x;
  const int lane = tid & 63, wv = tid >> 6;
  const int l16 = lane & 15, quad = lane >> 4;
  int bx = blockIdx.x, by = blockIdx.y;
  {  // bijective XCD chunk swizzle (nwg % 8 == 0 for all our grids)
    const int gx = gridDim.x;
    const int nwg = gx * gridDim.y;
    if ((nwg & 7) == 0) {
      const int f = by * gx + bx;
      const int q = nwg >> 3;
      const int wg = (f & 7) * q + (f >> 3);
      by = wg / gx;
      bx = wg - by * gx;
    }
  }
  const int m0 = by * 256, n0 = bx * (NI * 64);
  const int wm = (wv >> 2) * 128, wn = (wv & 3) * (NI * 16);
  const int nk = K >> 6;

  const u16* Ag = A + (size_t)m0 * K;
  const u16* Bg = Bt + (size_t)n0 * K;

#define STAGE(MAT, H, ST, P)                                                  \
  {                                                                           \
    const int tt = (ST) < nk ? (ST) : nk - 1; /* clamp: dummy loads */        \
    const int k0s = tt << 6;                                                  \
    u16* dst = &L[(MAT)*2 + (H)][P][0];                                       \
    const u16* srcp = (MAT) ? Bg : Ag;                                        \
    _Pragma("unroll") for (int j = 0; j < 2; ++j) {                           \
      const int li = wv * 2 + j;                                              \
      const int pr = li * 8 + (lane >> 3);                                    \
      const int bb = lane & 7;                                                \
      const int gg2 = bb ^ (pr & 7);                                          \
      const int rw = 2 * pr + (gg2 >> 2);                                     \
      load_lds16(srcp + (size_t)rw * K + k0s + (H)*32 + (gg2 & 3) * 8,        \
                 dst + li * 512 + lane * 8);                                  \
    }                                                                         \
  }

  // per-thread LDS byte addresses (buf0, half0); KK/CB add immediates:
  // A(kk,cb) at (kk*2+cb)*16384; B at 65536 + same.
  unsigned aaddr[2][4], baddr[NI];
  {
    const unsigned Lb = ldsoff(&L[0][0][0]);
#pragma unroll
    for (int MH = 0; MH < 2; ++MH)
#pragma unroll
      for (int mi = 0; mi < 4; ++mi) {
        const int R = wm + MH * 64 + mi * 16 + l16;
        const int p = R >> 1, g = (R & 1) * 4 + quad, b = g ^ (p & 7);
        aaddr[MH][mi] = Lb + (unsigned)(p * 64 + b * 8) * 2u;
      }
#pragma unroll
    for (int ni = 0; ni < NI; ++ni) {
      const int R = wn + ni * 16 + l16;
      const int p = R >> 1, g = (R & 1) * 4 + quad, b = g ^ (p & 7);
      baddr[ni] = Lb + 65536u + (unsigned)(p * 64 + b * 8) * 2u;
    }
  }

  f32x4 acc[8][NI] = {};

// One fat phase: read all frags for (CB,KK), stage two half-tiles, barrier,
// wait, 8xNI MFMA, counted vmcnt(8), barrier.
#define PHASE(CB, KK, S1M, S1H, S2M, S2H, ST, SP)                             \
  {                                                                           \
    bf16x8 af[2][4];                                                          \
    bf16x8 bfr[NI];                                                           \
    _Pragma("unroll") for (int mh = 0; mh < 2; ++mh)                          \
        _Pragma("unroll") for (int mi = 0; mi < 4; ++mi)                      \
            asm volatile("ds_read_b128 %0, %1 offset:%2"                      \
                         : "=v"(af[mh][mi])                                   \
                         : "v"(aaddr[mh][mi]),                                \
                           "i"((KK)*32768 + (CB)*16384));                     \
    _Pragma("unroll") for (int ni = 0; ni < NI; ++ni)                         \
        asm volatile("ds_read_b128 %0, %1 offset:%2"                          \
                     : "=v"(bfr[ni])                                          \
                     : "v"(baddr[ni]), "i"((KK)*32768 + (CB)*16384));         \
    STAGE(S1M, S1H, ST, SP);                                                  \
    STAGE(S2M, S2H, ST, SP);                                                  \
    __builtin_amdgcn_s_barrier();                                             \
    asm volatile("s_waitcnt lgkmcnt(0)");                                     \
    __builtin_amdgcn_sched_barrier(0);                                        \
    __builtin_amdgcn_s_setprio(1);                                            \
    _Pragma("unroll") for (int mh = 0; mh < 2; ++mh)                          \
        _Pragma("unroll") for (int mi = 0; mi < 4; ++mi)                      \
            _Pragma("unroll") for (int ni = 0; ni < NI; ++ni)                 \
                acc[mh * 4 + mi][ni] =                                        \
                    __builtin_amdgcn_mfma_f32_16x16x32_bf16(                  \
                        af[mh][mi], bfr[ni], acc[mh * 4 + mi][ni], 0, 0, 0);  \
    __builtin_amdgcn_s_setprio(0);                                            \
    asm volatile("s_waitcnt vmcnt(8)");                                       \
    __builtin_amdgcn_s_barrier();                                             \
  }

  // prologue: A0B0(t0), A1B1(t0), A0B0(t1) = 12 loads/thread; retire first 4
  // (A0B0(t0)) via vmcnt(8).
  STAGE(0, 0, 0, 0);
  STAGE(1, 0, 0, 0);
  STAGE(0, 1, 0, 0);
  STAGE(1, 1, 0, 0);
  STAGE(0, 0, 1, 1);
  STAGE(1, 0, 1, 1);
  asm volatile("s_waitcnt vmcnt(8)");
  __builtin_amdgcn_s_barrier();

  for (int t = 0; t < nk; t += 2) {  // nk even for all our shapes
    // tile t (buf 0)
    PHASE(0, 0, 0, 1, 1, 1, t + 1, 1)  // read kk0; stage A1B1(t+1)->buf1
    PHASE(0, 1, 0, 0, 1, 0, t + 2, 0)  // read kk1; stage A0B0(t+2)->buf0
    // tile t+1 (buf 1)
    PHASE(1, 0, 0, 1, 1, 1, t + 2, 0)  // read kk0; stage A1B1(t+2)->buf0
    PHASE(1, 1, 0, 0, 1, 0, t + 3, 1)  // read kk1; stage A0B0(t+3)->buf1
  }
#undef PHASE
#undef STAGE

  const int SL = 1 << rpbl;
#pragma unroll
  for (int mi = 0; mi < 8; ++mi) {
#pragma unroll
    for (int ni = 0; ni < NI; ++ni) {
#pragma unroll
      for (int r = 0; r < 4; ++r) {
        const int row = m0 + wm + mi * 16 + quad * 4 + r;
        const int col = n0 + wn + ni * 16 + l16;
        float vv = acc[mi][ni][r] + bias[col];
        if (EPI == 2) {
          ((u16*)C0)[(size_t)row * N + col] = f2bf(geluf(vv));
        } else if (EPI == 3) {
          const float partner = __shfl_xor(vv, 1);
          const int which = col >> 10;
          const int nn = col & 1023;
          const int h = nn >> 6, hd = nn & 63;
          const int b = row >> rpbl;
          const int s = row & (SL - 1);
          if (which == 2) {
            C2[(((size_t)b * HN + h) * SD + hd) * SL + s] = f2bf(vv);
          } else {
            const int p = hd >> 1;
            const float cv = rcos[s * 32 + p];
            const float sv2 = rsin[s * 32 + p];
            float o = (hd & 1) ? (partner * sv2 + vv * cv)
                               : (vv * cv - partner * sv2);
            if (which == 0) o *= QSC;
            u16* dst = (which == 0) ? (u16*)C0 : C1;
            dst[(((size_t)b * HN + h) * SL + s) * SD + hd] = f2bf(o);
          }
        } else {
          ((u16*)C0)[(size_t)row * N + col] = f2bf(vv);
        }
      }
    }
  }
}

// ---------------------------------------------------------------- attention
template <int CAUSAL>
__global__ __launch_bounds__(512, 4) void attn_kernel(
    const u16* __restrict__ q, const u16* __restrict__ k,
    const u16* __restrict__ vt, u16* __restrict__ out, int kv_len) {
  __shared__ u16 Qs[128][72], Ks[64][72], VTs[64][72];
  __shared__ u16 Ps[128][68];
  const int tid = threadIdx.x;
  const int lane = tid & 63, wv = tid >> 6;
  const int t2 = wv >> 2, w4 = wv & 3;
  const int l16 = lane & 15, quad = lane >> 4;
  const int bx = blockIdx.x, bh = blockIdx.y;
  const int qtA = bx;
  const int qtB = CAUSAL ? (31 - bx) : (bx + 16);
  const int qt = t2 ? qtB : qtA;
  const u16* qb = q + (size_t)bh * SEQ * SD;
  const u16* kb = k + (size_t)bh * kv_len * SD;
  const u16* vtb = vt + (size_t)bh * SD * kv_len;

#pragma unroll
  for (int it = 0; it < 2; ++it) {
    const int t = it * 512 + tid, r = t >> 3, c = (t & 7) * 8;
    const int qrow = (r < 64) ? (qtA * 64 + r) : (qtB * 64 + (r - 64));
    *(uint4*)&Qs[r][c] = *(const uint4*)&qb[(size_t)qrow * SD + c];
  }

  f32x4 o_acc[4] = {};
  float l_i[4] = {};

  const int ktiles = CAUSAL ? (qtB + 1) : ((kv_len + 63) >> 6);
  const int sr = tid >> 3, sc8 = (tid & 7) * 8;

  for (int kt = 0; kt < ktiles; ++kt) {
    const uint4 kd = *(const uint4*)&kb[((size_t)kt * 64 + sr) * SD + sc8];
    const uint4 vd = *(const uint4*)&vtb[(size_t)sr * kv_len + kt * 64 + sc8];
    __syncthreads();
    *(uint4*)&Ks[sr][sc8] = kd;
    *(uint4*)&VTs[sr][sc8] = vd;
    __syncthreads();

    if (kt <= qt) {
      const int roff = t2 * 64 + w4 * 16;
      f32x4 s_acc[4] = {};
#pragma unroll
      for (int kk = 0; kk < 64; kk += 32) {
        const bf16x8 aq = *(const bf16x8*)&Qs[roff + l16][kk + quad * 8];
#pragma unroll
        for (int ni = 0; ni < 4; ++ni) {
          const bf16x8 bk = *(const bf16x8*)&Ks[ni * 16 + l16][kk + quad * 8];
          s_acc[ni] = __builtin_amdgcn_mfma_f32_16x16x32_bf16(aq, bk, s_acc[ni],
                                                              0, 0, 0);
        }
      }
      float rsum[4] = {0.f, 0.f, 0.f, 0.f};
      const bool dg = CAUSAL && (kt == qt);
#pragma unroll
      for (int ni = 0; ni < 4; ++ni)
#pragma unroll
        for (int r = 0; r < 4; ++r) {
          float sv = s_acc[ni][r];
          if (dg && (ni * 16 + l16 > w4 * 16 + quad * 4 + r)) sv = -1e9f;
          const float pe = __builtin_amdgcn_exp2f(sv);
          rsum[r] += pe;
          Ps[wv * 16 + quad * 4 + r][ni * 16 + l16] =
              (u16)(__float_as_uint(pe) >> 16);
        }
#pragma unroll
      for (int r = 0; r < 4; ++r) {
#pragma unroll
        for (int dd = 1; dd < 16; dd <<= 1)
          rsum[r] += __shfl_xor(rsum[r], dd, 64);
        l_i[r] += rsum[r];
      }
#pragma unroll
      for (int kk = 0; kk < 64; kk += 32) {
        const bf16x8 ap = *(const bf16x8*)&Ps[wv * 16 + l16][kk + quad * 8];
#pragma unroll
        for (int ni = 0; ni < 4; ++ni) {
          const bf16x8 bv = *(const bf16x8*)&VTs[ni * 16 + l16][kk + quad * 8];
          o_acc[ni] = __builtin_amdgcn_mfma_f32_16x16x32_bf16(ap, bv, o_acc[ni],
                                                              0, 0, 0);
        }
      }
    }
  }

  const int b = bh >> 4, h = bh & 15;
#pragma unroll
  for (int r = 0; r < 4; ++r) {
    const float inv = 1.f / l_i[r];
    const int s = qt * 64 + w4 * 16 + quad * 4 + r;
#pragma unroll
    for (int ni = 0; ni < 4; ++ni)
      out[((size_t)b * SEQ + s) * DM + h * SD + ni * 16 + l16] =
          f2bf(o_acc[ni][r] * inv);
  }
}

// ---------------------------------------------------------------- launch
extern "C" void kernel_launch(void* const* d_in, const int* in_sizes, int n_in,
                              void* d_out, int out_size, void* d_ws,
                              size_t ws_size, hipStream_t stream) {
  (void)in_sizes;
  (void)n_in;
  (void)out_size;
  (void)ws_size;
  const float* tgt = (const float*)d_in[0];
  const float* mem = (const float*)d_in[1];
  const float* rc = (const float*)d_in[2];
  const float* rsn = (const float*)d_in[3];
  const float* W_qkv = (const float*)d_in[4];
  const float* b_qkv = (const float*)d_in[5];
  const float* W_o = (const float*)d_in[6];
  const float* b_o = (const float*)d_in[7];
  const float* Wq_c = (const float*)d_in[8];
  const float* bq_c = (const float*)d_in[9];
  const float* Wk_c = (const float*)d_in[10];
  const float* bk_c = (const float*)d_in[11];
  const float* Wv_c = (const float*)d_in[12];
  const float* bv_c = (const float*)d_in[13];
  const float* W_co = (const float*)d_in[14];
  const float* b_co = (const float*)d_in[15];
  const float* W1 = (const float*)d_in[16];
  const float* b1 = (const float*)d_in[17];
  const float* W2 = (const float*)d_in[18];
  const float* b2 = (const float*)d_in[19];
  const float* g1 = (const float*)d_in[20];
  const float* be1 = (const float*)d_in[21];
  const float* g2 = (const float*)d_in[22];
  const float* be2 = (const float*)d_in[23];
  const float* g3 = (const float*)d_in[24];
  const float* be3 = (const float*)d_in[25];

  const size_t M1 = 1048576;
  u16* w = (u16*)d_ws;
  u16* WTqkv = w;
  u16* WTo = w + 3 * M1;
  u16* WTqc = w + 4 * M1;
  u16* WTkc = w + 5 * M1;
  u16* WTvc = w + 6 * M1;
  u16* WTco = w + 7 * M1;
  u16* WT1 = w;
  u16* WT2 = w + 4 * M1;
  u16* xb = w + 8 * M1;
  u16* qb = w + 12 * M1;
  u16* kb = w + 16 * M1;
  u16* vbT = w + 20 * M1;
  u16* at = w + 24 * M1;
  u16* kc = w + 28 * M1;
  u16* vcT = kc + 131072;
  u16* memb = vcT + 131072;
  u16* ffh = qb;
  float* res = (float*)d_out;

  dim3 blk(256), blk512(512);
  prep1<<<2176, blk, 0, stream>>>(W_qkv, W_o, Wq_c, Wk_c, Wv_c, W_co, WTqkv,
                                  WTo, WTqc, WTkc, WTvc, WTco, mem, memb);

  // --- self-attention block
  ln_kernel<<<4096, blk, 0, stream>>>(tgt, g1, be1, xb);
  gemm8p<3, 3><<<dim3(16, 16), blk512, 0, stream>>>(
      xb, WTqkv, b_qkv, qb, kb, vbT, 4096, 3072, 1024, 11, rc, rsn);
  attn_kernel<1><<<dim3(16, 32), blk512, 0, stream>>>(qb, kb, vbT, at, 2048);
  gemm_bt<1, 64><<<dim3(8, 64), blk, 0, stream>>>(at, WTo, b_o, tgt, res,
                                                  nullptr, nullptr, 4096, 1024,
                                                  1024, 0, 1.f, nullptr,
                                                  nullptr);
  // --- cross-attention block
  ln_kernel<<<4096, blk, 0, stream>>>(res, g2, be2, xb);
  gemm_bt<4, 64><<<dim3(8, 64), blk, 0, stream>>>(
      xb, WTqc, bq_c, nullptr, qb, nullptr, nullptr, 4096, 1024, 1024, 11, QSC,
      nullptr, nullptr);
  gemm_bt<6, 64><<<dim3(8, 2, 2), blk, 0, stream>>>(
      memb, WTkc, bk_c, bv_c, kc, WTvc, vcT, 128, 1024, 1024, 6, 1.f, nullptr,
      nullptr);
  attn_kernel<0><<<dim3(16, 32), blk512, 0, stream>>>(qb, kc, vcT, at, 64);
  gemm_bt<1, 64><<<dim3(8, 64), blk, 0, stream>>>(at, WTco, b_co, res, res,
                                                  nullptr, nullptr, 4096, 1024,
                                                  1024, 0, 1.f, nullptr,
                                                  nullptr);
  // --- FFN block
  prep2<<<2048, blk, 0, stream>>>(W1, W2, WT1, WT2);
  ln_kernel<<<4096, blk, 0, stream>>>(res, g3, be3, xb);
  gemm8p<2, 4><<<dim3(16, 16), blk512, 0, stream>>>(xb, WT1, b1, ffh, nullptr,
                                                    nullptr, 4096, 4096, 1024,
                                                    0, nullptr, nullptr);
  gemm_bt<1, 64><<<dim3(8, 64), blk, 0, stream>>>(ffh, WT2, b2, res, res,
                                                  nullptr, nullptr, 4096, 1024,
                                                  4096, 0, 1.f, nullptr,
                                                  nullptr);
}

// Round 8
// 455.644 us; speedup vs baseline: 1.0826x; 1.0075x over previous
//
#include <hip/hip_runtime.h>

typedef unsigned short u16;
typedef short bf16x8 __attribute__((ext_vector_type(8)));
typedef float f32x4 __attribute__((ext_vector_type(4)));

#define HN 16
#define SD 64
#define SEQ 2048
#define DM 1024
#define QSC 0.18033688f  // 0.125 * log2(e): softmax done in exp2 domain

__device__ __forceinline__ float bf2f(u16 h) {
  return __uint_as_float(((unsigned int)h) << 16);
}
__device__ __forceinline__ u16 f2bf(float f) {
  unsigned int x = __float_as_uint(f);
  x += 0x7fffu + ((x >> 16) & 1u);
  return (u16)(x >> 16);
}
__device__ __forceinline__ float geluf(float x) {
  return 0.5f * x * (1.0f + erff(x * 0.70710678118654752f));
}
__device__ __forceinline__ void load_lds16(const u16* g, u16* l) {
  __builtin_amdgcn_global_load_lds(
      (const __attribute__((address_space(1))) void*)g,
      (__attribute__((address_space(3))) void*)l, 16, 0, 0);
}
// LDS byte offset of a generic pointer known to point into LDS.
__device__ __forceinline__ unsigned ldsoff(const u16* p) {
  return (unsigned)(unsigned long long)(
      const __attribute__((address_space(3))) u16*)p;
}

// ----------------------------------------------------- transpose tile (dev)
__device__ __forceinline__ void trans_tile(const float* __restrict__ in,
                                           u16* __restrict__ out, int K, int N,
                                           int tx, int ty, int tid,
                                           u16 (*T)[72]) {
  const int n0 = tx * 64, k0 = ty * 64;
#pragma unroll
  for (int it = 0; it < 2; ++it) {
    const int t = it * 256 + tid, r = t >> 3, c = (t & 7) * 8;
    const float* src = &in[(size_t)(k0 + r) * N + n0 + c];
    float4 d0 = *(const float4*)src;
    float4 d1 = *(const float4*)(src + 4);
    T[r][c + 0] = f2bf(d0.x);
    T[r][c + 1] = f2bf(d0.y);
    T[r][c + 2] = f2bf(d0.z);
    T[r][c + 3] = f2bf(d0.w);
    T[r][c + 4] = f2bf(d1.x);
    T[r][c + 5] = f2bf(d1.y);
    T[r][c + 6] = f2bf(d1.z);
    T[r][c + 7] = f2bf(d1.w);
  }
  __syncthreads();
#pragma unroll
  for (int it = 0; it < 2; ++it) {
    const int t = it * 256 + tid, r = t >> 3, c = (t & 7) * 8;
    uint4 d;
    u16* p = (u16*)&d;
#pragma unroll
    for (int j = 0; j < 8; ++j) p[j] = T[c + j][r];
    *(uint4*)&out[(size_t)(n0 + r) * K + k0 + c] = d;
  }
}

// ------------------------------------------------- prep1: 6 WT + mem f2b
__global__ __launch_bounds__(256) void prep1(
    const float* __restrict__ Wqkv, const float* __restrict__ Wo,
    const float* __restrict__ Wqc, const float* __restrict__ Wkc,
    const float* __restrict__ Wvc, const float* __restrict__ Wco,
    u16* __restrict__ Tqkv, u16* __restrict__ To, u16* __restrict__ Tqc,
    u16* __restrict__ Tkc, u16* __restrict__ Tvc, u16* __restrict__ Tco,
    const float* __restrict__ mem, u16* __restrict__ memb) {
  __shared__ u16 T[64][72];
  const int t = blockIdx.x, tid = threadIdx.x;
  if (t < 768) {
    trans_tile(Wqkv, Tqkv, 1024, 3072, t % 48, t / 48, tid, T);
    return;
  }
  if (t < 2048) {
    const int u = t - 768, m = u >> 8, sub = u & 255;
    const float* in;
    u16* out;
    if (m == 0) { in = Wo; out = To; }
    else if (m == 1) { in = Wqc; out = Tqc; }
    else if (m == 2) { in = Wkc; out = Tkc; }
    else if (m == 3) { in = Wvc; out = Tvc; }
    else { in = Wco; out = Tco; }
    trans_tile(in, out, 1024, 1024, sub & 15, sub >> 4, tid, T);
    return;
  }
  const int i = ((t - 2048) * 256 + tid) * 4;
  float4 d = *(const float4*)&mem[i];
  uint2 o;
  u16* po = (u16*)&o;
  po[0] = f2bf(d.x);
  po[1] = f2bf(d.y);
  po[2] = f2bf(d.z);
  po[3] = f2bf(d.w);
  *(uint2*)&memb[i] = o;
}

// ------------------------------------------------- prep2: W1 + W2 transpose
__global__ __launch_bounds__(256) void prep2(const float* __restrict__ W1,
                                             const float* __restrict__ W2,
                                             u16* __restrict__ T1,
                                             u16* __restrict__ T2) {
  __shared__ u16 T[64][72];
  const int t = blockIdx.x, tid = threadIdx.x;
  if (t < 1024) {
    trans_tile(W1, T1, 1024, 4096, t & 63, t >> 6, tid, T);
  } else {
    const int u = t - 1024;
    trans_tile(W2, T2, 4096, 1024, u & 15, u >> 4, tid, T);
  }
}

// ---------------------------------------------------------------- layernorm
__global__ __launch_bounds__(256) void ln_kernel(
    const float* __restrict__ x, const float* __restrict__ g,
    const float* __restrict__ be, u16* __restrict__ y) {
  const int row = blockIdx.x, tid = threadIdx.x;
  const float* xr = x + (size_t)row * DM;
  float4 d = *(const float4*)&xr[tid * 4];
  float v[4] = {d.x, d.y, d.z, d.w};
  float s1 = 0.f, s2 = 0.f;
#pragma unroll
  for (int j = 0; j < 4; ++j) {
    s1 += v[j];
    s2 += v[j] * v[j];
  }
#pragma unroll
  for (int dd = 1; dd < 64; dd <<= 1) {
    s1 += __shfl_xor(s1, dd, 64);
    s2 += __shfl_xor(s2, dd, 64);
  }
  __shared__ float p1[4], p2[4];
  const int lane = tid & 63, wv = tid >> 6;
  if (lane == 0) {
    p1[wv] = s1;
    p2[wv] = s2;
  }
  __syncthreads();
  s1 = p1[0] + p1[1] + p1[2] + p1[3];
  s2 = p2[0] + p2[1] + p2[2] + p2[3];
  const float mu = s1 * (1.f / DM);
  const float rs = rsqrtf(fmaxf(s2 * (1.f / DM) - mu * mu, 0.f) + 1e-5f);
  float4 gg = *(const float4*)&g[tid * 4];
  float4 bb = *(const float4*)&be[tid * 4];
  const float gv[4] = {gg.x, gg.y, gg.z, gg.w};
  const float bv[4] = {bb.x, bb.y, bb.z, bb.w};
  uint2 o;
  u16* po = (u16*)&o;
#pragma unroll
  for (int j = 0; j < 4; ++j) po[j] = f2bf((v[j] - mu) * rs * gv[j] + bv[j]);
  *(uint2*)&y[(size_t)row * DM + tid * 4] = o;
}

// ---------------------------------------------------------------- GEMM (r13)
// TM x 128 tile, BK=64, 4 waves, DOUBLE-BUFFERED with ONE barrier per K-tile
// (T3-minimum recipe): STAGE(t+1 -> buf^1) issued FIRST, asm ds_read frags of
// buf, lgkmcnt(0)+sched_barrier, MFMA, vmcnt(0), barrier.
template <int EPI, int TM>
__global__ __launch_bounds__(256) void gemm_bt(
    const u16* __restrict__ A, const u16* __restrict__ Bt,
    const float* __restrict__ bias, const float* __restrict__ resid,
    void* __restrict__ C0, u16* __restrict__ C1, u16* __restrict__ C2, int M,
    int N, int K, int rpbl, float sc, const float* __restrict__ rcos,
    const float* __restrict__ rsin) {
  constexpr int MI = TM / 32;
  __shared__ __align__(16) u16 As[2][TM][64];
  __shared__ __align__(16) u16 Bs[2][128][64];
  const int tid = threadIdx.x;
  const int lane = tid & 63, wv = tid >> 6;
  const int l16 = lane & 15, quad = lane >> 4;

  if (EPI == 6 && blockIdx.z) {
    Bt = (const u16*)C1;
    bias = resid;
  }

  int bx = blockIdx.x, by = blockIdx.y;
  const int gx = gridDim.x, gy = gridDim.y;
  if ((gy & 7) == 0) {
    const int f = by * gx + bx;
    const int c = f & 7, j = f >> 3;
    const int jm = j / gx;
    by = c * (gy >> 3) + jm;
    bx = j - jm * gx;
  }
  const int m0 = by * TM, n0 = bx * 128;
  const int wm = (wv >> 1) * (TM / 2), wn = (wv & 1) * 64;
  const int nk = K >> 6;

  const int srow = lane >> 3;
  const int sblk = (lane & 7) ^ srow;
  const u16* ag[MI];
  const u16* bg[4];
  u16* la[MI];
  u16* lb[4];
#pragma unroll
  for (int i = 0; i < MI; ++i) {
    const int r0 = i * 32 + wv * 8;
    ag[i] = A + (size_t)(m0 + r0 + srow) * K + sblk * 8;
    la[i] = &As[0][r0][0] + lane * 8;
  }
#pragma unroll
  for (int i = 0; i < 4; ++i) {
    const int r0 = i * 32 + wv * 8;
    bg[i] = Bt + (size_t)(n0 + r0 + srow) * K + sblk * 8;
    lb[i] = &Bs[0][r0][0] + lane * 8;
  }

  // fragment LDS byte addresses (buf0); buf adds literal imm in the asm.
  unsigned aad[2][MI], bad[2][4];
#pragma unroll
  for (int kk = 0; kk < 2; ++kk) {
#pragma unroll
    for (int mi = 0; mi < MI; ++mi) {
      const int row = wm + mi * 16 + l16;
      const int blk = (kk * 4 + quad) ^ (row & 7);
      aad[kk][mi] = ldsoff(&As[0][0][0]) + (unsigned)(row * 128 + blk * 16);
    }
#pragma unroll
    for (int ni = 0; ni < 4; ++ni) {
      const int row = wn + ni * 16 + l16;
      const int blk = (kk * 4 + quad) ^ (row & 7);
      bad[kk][ni] = ldsoff(&Bs[0][0][0]) + (unsigned)(row * 128 + blk * 16);
    }
  }

  f32x4 acc[MI][4] = {};

#define STB(P, ST)                                                            \
  {                                                                           \
    const int tt = (ST) < nk ? (ST) : nk - 1;                                 \
    const int k0s = tt << 6;                                                  \
    _Pragma("unroll") for (int i = 0; i < MI; ++i)                            \
        load_lds16(ag[i] + k0s, la[i] + (P) * (TM * 64));                     \
    _Pragma("unroll") for (int i = 0; i < 4; ++i)                             \
        load_lds16(bg[i] + k0s, lb[i] + (P) * 8192);                          \
  }

#define TILEB(CB, NP, ST)                                                     \
  {                                                                           \
    STB(NP, ST);                                                              \
    bf16x8 afr[2][MI], bfr[2][4];                                             \
    _Pragma("unroll") for (int kk = 0; kk < 2; ++kk) {                        \
      _Pragma("unroll") for (int mi = 0; mi < MI; ++mi)                       \
          asm volatile("ds_read_b128 %0, %1 offset:%2"                        \
                       : "=v"(afr[kk][mi])                                    \
                       : "v"(aad[kk][mi]), "i"((CB) * (TM * 128)));           \
      _Pragma("unroll") for (int ni = 0; ni < 4; ++ni)                        \
          asm volatile("ds_read_b128 %0, %1 offset:%2"                        \
                       : "=v"(bfr[kk][ni])                                    \
                       : "v"(bad[kk][ni]), "i"((CB)*16384));                  \
    }                                                                         \
    asm volatile("s_waitcnt lgkmcnt(0)");                                     \
    __builtin_amdgcn_sched_barrier(0);                                        \
    __builtin_amdgcn_s_setprio(1);                                            \
    _Pragma("unroll") for (int kk = 0; kk < 2; ++kk)                          \
        _Pragma("unroll") for (int mi = 0; mi < MI; ++mi)                     \
            _Pragma("unroll") for (int ni = 0; ni < 4; ++ni) acc[mi][ni] =    \
                __builtin_amdgcn_mfma_f32_16x16x32_bf16(                      \
                    afr[kk][mi], bfr[kk][ni], acc[mi][ni], 0, 0, 0);          \
    __builtin_amdgcn_s_setprio(0);                                            \
    asm volatile("s_waitcnt vmcnt(0)");                                       \
    __builtin_amdgcn_s_barrier();                                             \
  }

  STB(0, 0);
  asm volatile("s_waitcnt vmcnt(0)");
  __builtin_amdgcn_s_barrier();
  for (int t = 0; t < nk; t += 2) {  // nk even (16 or 64)
    TILEB(0, 1, t + 1)
    TILEB(1, 0, t + 2)
  }
#undef TILEB
#undef STB

  const int SL = 1 << rpbl;
#pragma unroll
  for (int mi = 0; mi < MI; ++mi) {
#pragma unroll
    for (int ni = 0; ni < 4; ++ni) {
#pragma unroll
      for (int r = 0; r < 4; ++r) {
        const int row = m0 + wm + mi * 16 + quad * 4 + r;
        const int col = n0 + wn + ni * 16 + l16;
        float vv = acc[mi][ni][r] + bias[col];
        if (EPI == 1) {
          vv += resid[(size_t)row * N + col];
          ((float*)C0)[(size_t)row * N + col] = vv;
        } else if (EPI == 2) {
          ((u16*)C0)[(size_t)row * N + col] = f2bf(geluf(vv));
        } else if (EPI == 3) {
          const float partner = __shfl_xor(vv, 1);
          const int which = col >> 10;
          const int nn = col & 1023;
          const int h = nn >> 6, hd = nn & 63;
          const int b = row >> rpbl;
          const int s = row & (SL - 1);
          if (which == 2) {
            C2[(((size_t)b * HN + h) * SD + hd) * SL + s] = f2bf(vv);
          } else {
            const int p = hd >> 1;
            const float cv = rcos[s * 32 + p];
            const float sv2 = rsin[s * 32 + p];
            float o = (hd & 1) ? (partner * sv2 + vv * cv)
                               : (vv * cv - partner * sv2);
            if (which == 0) o *= QSC;
            u16* dst = (which == 0) ? (u16*)C0 : C1;
            dst[(((size_t)b * HN + h) * SL + s) * SD + hd] = f2bf(o);
          }
        } else if (EPI == 4) {
          vv *= sc;
          const int h = col >> 6, hd = col & 63;
          const int b = row >> rpbl;
          const int s = row & (SL - 1);
          ((u16*)C0)[(((size_t)b * HN + h) * SL + s) * SD + hd] = f2bf(vv);
        } else if (EPI == 5) {
          const int h = col >> 6, hd = col & 63;
          const int b = row >> rpbl;
          const int s = row & (SL - 1);
          ((u16*)C0)[(((size_t)b * HN + h) * SD + hd) * SL + s] = f2bf(vv);
        } else if (EPI == 6) {
          const int h = col >> 6, hd = col & 63;
          const int b = row >> rpbl;
          const int s = row & (SL - 1);
          if (blockIdx.z == 0)
            ((u16*)C0)[(((size_t)b * HN + h) * SL + s) * SD + hd] = f2bf(vv);
          else
            C2[(((size_t)b * HN + h) * SD + hd) * SL + s] = f2bf(vv);
        } else {
          ((u16*)C0)[(size_t)row * N + col] = f2bf(vv);
        }
      }
    }
  }
}

// ---------------------------------------------------------------- GEMM 8p
// r14 = r12-exact gemm8p (best measured): 2 fat phases/K-tile, counted
// vmcnt(8), literal parities, inline-asm ds_read. See r14 notes.
template <int EPI, int NI>
__global__ __launch_bounds__(512, 2) void gemm8p(
    const u16* __restrict__ A, const u16* __restrict__ Bt,
    const float* __restrict__ bias, void* __restrict__ C0,
    u16* __restrict__ C1, u16* __restrict__ C2, int M, int N, int K, int rpbl,
    const float* __restrict__ rcos, const float* __restrict__ rsin) {
  __shared__ __align__(16) u16 L[4][2][8192];  // [A0,A1,B0,B1][buf][128x64]
  const int tid = threadIdx.x;
  const int lane = tid & 63, wv = tid >> 6;
  const int l16 = lane & 15, quad = lane >> 4;
  int bx = blockIdx.x, by = blockIdx.y;
  {  // bijective XCD chunk swizzle (nwg % 8 == 0 for all our grids)
    const int gx = gridDim.x;
    const int nwg = gx * gridDim.y;
    if ((nwg & 7) == 0) {
      const int f = by * gx + bx;
      const int q = nwg >> 3;
      const int wg = (f & 7) * q + (f >> 3);
      by = wg / gx;
      bx = wg - by * gx;
    }
  }
  const int m0 = by * 256, n0 = bx * (NI * 64);
  const int wm = (wv >> 2) * 128, wn = (wv & 3) * (NI * 16);
  const int nk = K >> 6;

  const u16* Ag = A + (size_t)m0 * K;
  const u16* Bg = Bt + (size_t)n0 * K;

#define STAGE(MAT, H, ST, P)                                                  \
  {                                                                           \
    const int tt = (ST) < nk ? (ST) : nk - 1; /* clamp: dummy loads */        \
    const int k0s = tt << 6;                                                  \
    u16* dst = &L[(MAT)*2 + (H)][P][0];                                       \
    const u16* srcp = (MAT) ? Bg : Ag;                                        \
    _Pragma("unroll") for (int j = 0; j < 2; ++j) {                           \
      const int li = wv * 2 + j;                                              \
      const int pr = li * 8 + (lane >> 3);                                    \
      const int bb = lane & 7;                                                \
      const int gg2 = bb ^ (pr & 7);                                          \
      const int rw = 2 * pr + (gg2 >> 2);                                     \
      load_lds16(srcp + (size_t)rw * K + k0s + (H)*32 + (gg2 & 3) * 8,        \
                 dst + li * 512 + lane * 8);                                  \
    }                                                                         \
  }

  unsigned aaddr[2][4], baddr[NI];
  {
    const unsigned Lb = ldsoff(&L[0][0][0]);
#pragma unroll
    for (int MH = 0; MH < 2; ++MH)
#pragma unroll
      for (int mi = 0; mi < 4; ++mi) {
        const int R = wm + MH * 64 + mi * 16 + l16;
        const int p = R >> 1, g = (R & 1) * 4 + quad, b = g ^ (p & 7);
        aaddr[MH][mi] = Lb + (unsigned)(p * 64 + b * 8) * 2u;
      }
#pragma unroll
    for (int ni = 0; ni < NI; ++ni) {
      const int R = wn + ni * 16 + l16;
      const int p = R >> 1, g = (R & 1) * 4 + quad, b = g ^ (p & 7);
      baddr[ni] = Lb + 65536u + (unsigned)(p * 64 + b * 8) * 2u;
    }
  }

  f32x4 acc[8][NI] = {};

#define PHASE(CB, KK, S1M, S1H, S2M, S2H, ST, SP)                             \
  {                                                                           \
    bf16x8 af[2][4];                                                          \
    bf16x8 bfr[NI];                                                           \
    _Pragma("unroll") for (int mh = 0; mh < 2; ++mh)                          \
        _Pragma("unroll") for (int mi = 0; mi < 4; ++mi)                      \
            asm volatile("ds_read_b128 %0, %1 offset:%2"                      \
                         : "=v"(af[mh][mi])                                   \
                         : "v"(aaddr[mh][mi]),                                \
                           "i"((KK)*32768 + (CB)*16384));                     \
    _Pragma("unroll") for (int ni = 0; ni < NI; ++ni)                         \
        asm volatile("ds_read_b128 %0, %1 offset:%2"                          \
                     : "=v"(bfr[ni])                                          \
                     : "v"(baddr[ni]), "i"((KK)*32768 + (CB)*16384));         \
    STAGE(S1M, S1H, ST, SP);                                                  \
    STAGE(S2M, S2H, ST, SP);                                                  \
    __builtin_amdgcn_s_barrier();                                             \
    asm volatile("s_waitcnt lgkmcnt(0)");                                     \
    __builtin_amdgcn_sched_barrier(0);                                        \
    __builtin_amdgcn_s_setprio(1);                                            \
    _Pragma("unroll") for (int mh = 0; mh < 2; ++mh)                          \
        _Pragma("unroll") for (int mi = 0; mi < 4; ++mi)                      \
            _Pragma("unroll") for (int ni = 0; ni < NI; ++ni)                 \
                acc[mh * 4 + mi][ni] =                                        \
                    __builtin_amdgcn_mfma_f32_16x16x32_bf16(                  \
                        af[mh][mi], bfr[ni], acc[mh * 4 + mi][ni], 0, 0, 0);  \
    __builtin_amdgcn_s_setprio(0);                                            \
    asm volatile("s_waitcnt vmcnt(8)");                                       \
    __builtin_amdgcn_s_barrier();                                             \
  }

  STAGE(0, 0, 0, 0);
  STAGE(1, 0, 0, 0);
  STAGE(0, 1, 0, 0);
  STAGE(1, 1, 0, 0);
  STAGE(0, 0, 1, 1);
  STAGE(1, 0, 1, 1);
  asm volatile("s_waitcnt vmcnt(8)");
  __builtin_amdgcn_s_barrier();

  for (int t = 0; t < nk; t += 2) {  // nk even for all our shapes
    PHASE(0, 0, 0, 1, 1, 1, t + 1, 1)
    PHASE(0, 1, 0, 0, 1, 0, t + 2, 0)
    PHASE(1, 0, 0, 1, 1, 1, t + 2, 0)
    PHASE(1, 1, 0, 0, 1, 0, t + 3, 1)
  }
#undef PHASE
#undef STAGE

  const int SL = 1 << rpbl;
#pragma unroll
  for (int mi = 0; mi < 8; ++mi) {
#pragma unroll
    for (int ni = 0; ni < NI; ++ni) {
#pragma unroll
      for (int r = 0; r < 4; ++r) {
        const int row = m0 + wm + mi * 16 + quad * 4 + r;
        const int col = n0 + wn + ni * 16 + l16;
        float vv = acc[mi][ni][r] + bias[col];
        if (EPI == 2) {
          ((u16*)C0)[(size_t)row * N + col] = f2bf(geluf(vv));
        } else if (EPI == 3) {
          const float partner = __shfl_xor(vv, 1);
          const int which = col >> 10;
          const int nn = col & 1023;
          const int h = nn >> 6, hd = nn & 63;
          const int b = row >> rpbl;
          const int s = row & (SL - 1);
          if (which == 2) {
            C2[(((size_t)b * HN + h) * SD + hd) * SL + s] = f2bf(vv);
          } else {
            const int p = hd >> 1;
            const float cv = rcos[s * 32 + p];
            const float sv2 = rsin[s * 32 + p];
            float o = (hd & 1) ? (partner * sv2 + vv * cv)
                               : (vv * cv - partner * sv2);
            if (which == 0) o *= QSC;
            u16* dst = (which == 0) ? (u16*)C0 : C1;
            dst[(((size_t)b * HN + h) * SL + s) * SD + hd] = f2bf(o);
          }
        } else {
          ((u16*)C0)[(size_t)row * N + col] = f2bf(vv);
        }
      }
    }
  }
}

// ---------------------------------------------------------------- attention
// r15: (1) XCD swizzle: each XCD owns 4 heads x all 16 q-tile blocks, so a
// head's K/V (512KB) stays in its 4MB L2 (was: all 8 XCDs fetched every
// head -> 71.6MB FETCH). (2) XOR-block LDS swizzle replaces +8/+4 pads
// (4.87M bank-conflict cycles -> ~0; LDS 54.3->48KB = 3 blocks/CU).
// (3) T14 prefetch split: next tile's K/V global loads issued right after
// the LDS write, in flight across the compute phase.
template <int CAUSAL>
__global__ __launch_bounds__(512, 4) void attn_kernel(
    const u16* __restrict__ q, const u16* __restrict__ k,
    const u16* __restrict__ vt, u16* __restrict__ out, int kv_len) {
  __shared__ __align__(16) u16 Qs[128][64], Ks[64][64], VTs[64][64];
  __shared__ __align__(16) u16 Ps[128][64];
  const int tid = threadIdx.x;
  const int lane = tid & 63, wv = tid >> 6;
  const int t2 = wv >> 2, w4 = wv & 3;
  const int l16 = lane & 15, quad = lane >> 4;
  // XCD swizzle: linear id l -> xcd c = l&7 (assumed rr); head = c + 8*(j>>4)
  int bx, bh;
  {
    const int l = blockIdx.y * 16 + blockIdx.x;
    const int c = l & 7, j = l >> 3;
    bh = c + 8 * (j >> 4);
    bx = j & 15;
  }
  const int qtA = bx;
  const int qtB = CAUSAL ? (31 - bx) : (bx + 16);
  const int qt = t2 ? qtB : qtA;
  const u16* qb = q + (size_t)bh * SEQ * SD;
  const u16* kb = k + (size_t)bh * kv_len * SD;
  const u16* vtb = vt + (size_t)bh * SD * kv_len;

  // stage Q (swizzled): rows 0..63 = tile A, 64..127 = tile B
#pragma unroll
  for (int it = 0; it < 2; ++it) {
    const int t = it * 512 + tid, r = t >> 3, cb = t & 7;
    const int qrow = (r < 64) ? (qtA * 64 + r) : (qtB * 64 + (r - 64));
    *(uint4*)&Qs[r][(cb ^ (r & 7)) * 8] =
        *(const uint4*)&qb[(size_t)qrow * SD + cb * 8];
  }

  f32x4 o_acc[4] = {};
  float l_i[4] = {};

  const int ktiles = CAUSAL ? (qtB + 1) : ((kv_len + 63) >> 6);
  const int sr = tid >> 3, scb = tid & 7;
  const int swb = (scb ^ (sr & 7)) * 8;

  uint4 kd = *(const uint4*)&kb[(size_t)sr * SD + scb * 8];
  uint4 vd = *(const uint4*)&vtb[(size_t)sr * kv_len + scb * 8];

  for (int kt = 0; kt < ktiles; ++kt) {
    __syncthreads();
    *(uint4*)&Ks[sr][swb] = kd;
    *(uint4*)&VTs[sr][swb] = vd;
    __syncthreads();
    if (kt + 1 < ktiles) {  // prefetch: in flight across compute
      kd = *(const uint4*)&kb[((size_t)(kt + 1) * 64 + sr) * SD + scb * 8];
      vd = *(const uint4*)&vtb[(size_t)sr * kv_len + (kt + 1) * 64 + scb * 8];
    }

    if (kt <= qt) {  // wave-uniform causal participation
      const int roff = t2 * 64 + w4 * 16;
      const int qrw = roff + l16;
      f32x4 s_acc[4] = {};
#pragma unroll
      for (int kk = 0; kk < 2; ++kk) {
        const bf16x8 aq =
            *(const bf16x8*)&Qs[qrw][((kk * 4 + quad) ^ (qrw & 7)) * 8];
#pragma unroll
        for (int ni = 0; ni < 4; ++ni) {
          const int krw = ni * 16 + l16;
          const bf16x8 bk =
              *(const bf16x8*)&Ks[krw][((kk * 4 + quad) ^ (krw & 7)) * 8];
          s_acc[ni] = __builtin_amdgcn_mfma_f32_16x16x32_bf16(aq, bk, s_acc[ni],
                                                              0, 0, 0);
        }
      }
      float rsum[4] = {0.f, 0.f, 0.f, 0.f};
      const bool dg = CAUSAL && (kt == qt);
#pragma unroll
      for (int ni = 0; ni < 4; ++ni) {
        const int colb = ni * 2 + (l16 >> 3);
#pragma unroll
        for (int r = 0; r < 4; ++r) {
          float sv = s_acc[ni][r];
          if (dg && (ni * 16 + l16 > w4 * 16 + quad * 4 + r)) sv = -1e9f;
          const float pe = __builtin_amdgcn_exp2f(sv);
          rsum[r] += pe;
          const int prow = wv * 16 + quad * 4 + r;
          Ps[prow][((colb ^ (prow & 7)) * 8) + (l16 & 7)] =
              (u16)(__float_as_uint(pe) >> 16);
        }
      }
#pragma unroll
      for (int r = 0; r < 4; ++r) {
#pragma unroll
        for (int dd = 1; dd < 16; dd <<= 1)
          rsum[r] += __shfl_xor(rsum[r], dd, 64);
        l_i[r] += rsum[r];
      }
      const int prw = wv * 16 + l16;
#pragma unroll
      for (int kk = 0; kk < 2; ++kk) {
        const bf16x8 ap =
            *(const bf16x8*)&Ps[prw][((kk * 4 + quad) ^ (prw & 7)) * 8];
#pragma unroll
        for (int ni = 0; ni < 4; ++ni) {
          const int vrw = ni * 16 + l16;
          const bf16x8 bv =
              *(const bf16x8*)&VTs[vrw][((kk * 4 + quad) ^ (vrw & 7)) * 8];
          o_acc[ni] = __builtin_amdgcn_mfma_f32_16x16x32_bf16(ap, bv, o_acc[ni],
                                                              0, 0, 0);
        }
      }
    }
  }

  const int b = bh >> 4, h = bh & 15;
#pragma unroll
  for (int r = 0; r < 4; ++r) {
    const float inv = 1.f / l_i[r];
    const int s = qt * 64 + w4 * 16 + quad * 4 + r;
#pragma unroll
    for (int ni = 0; ni < 4; ++ni)
      out[((size_t)b * SEQ + s) * DM + h * SD + ni * 16 + l16] =
          f2bf(o_acc[ni][r] * inv);
  }
}

// ---------------------------------------------------------------- launch
extern "C" void kernel_launch(void* const* d_in, const int* in_sizes, int n_in,
                              void* d_out, int out_size, void* d_ws,
                              size_t ws_size, hipStream_t stream) {
  (void)in_sizes;
  (void)n_in;
  (void)out_size;
  (void)ws_size;
  const float* tgt = (const float*)d_in[0];
  const float* mem = (const float*)d_in[1];
  const float* rc = (const float*)d_in[2];
  const float* rsn = (const float*)d_in[3];
  const float* W_qkv = (const float*)d_in[4];
  const float* b_qkv = (const float*)d_in[5];
  const float* W_o = (const float*)d_in[6];
  const float* b_o = (const float*)d_in[7];
  const float* Wq_c = (const float*)d_in[8];
  const float* bq_c = (const float*)d_in[9];
  const float* Wk_c = (const float*)d_in[10];
  const float* bk_c = (const float*)d_in[11];
  const float* Wv_c = (const float*)d_in[12];
  const float* bv_c = (const float*)d_in[13];
  const float* W_co = (const float*)d_in[14];
  const float* b_co = (const float*)d_in[15];
  const float* W1 = (const float*)d_in[16];
  const float* b1 = (const float*)d_in[17];
  const float* W2 = (const float*)d_in[18];
  const float* b2 = (const float*)d_in[19];
  const float* g1 = (const float*)d_in[20];
  const float* be1 = (const float*)d_in[21];
  const float* g2 = (const float*)d_in[22];
  const float* be2 = (const float*)d_in[23];
  const float* g3 = (const float*)d_in[24];
  const float* be3 = (const float*)d_in[25];

  const size_t M1 = 1048576;
  u16* w = (u16*)d_ws;
  u16* WTqkv = w;
  u16* WTo = w + 3 * M1;
  u16* WTqc = w + 4 * M1;
  u16* WTkc = w + 5 * M1;
  u16* WTvc = w + 6 * M1;
  u16* WTco = w + 7 * M1;
  u16* WT1 = w;
  u16* WT2 = w + 4 * M1;
  u16* xb = w + 8 * M1;
  u16* qb = w + 12 * M1;
  u16* kb = w + 16 * M1;
  u16* vbT = w + 20 * M1;
  u16* at = w + 24 * M1;
  u16* kc = w + 28 * M1;
  u16* vcT = kc + 131072;
  u16* memb = vcT + 131072;
  u16* ffh = qb;
  float* res = (float*)d_out;

  dim3 blk(256), blk512(512);
  prep1<<<2176, blk, 0, stream>>>(W_qkv, W_o, Wq_c, Wk_c, Wv_c, W_co, WTqkv,
                                  WTo, WTqc, WTkc, WTvc, WTco, mem, memb);

  // --- self-attention block
  ln_kernel<<<4096, blk, 0, stream>>>(tgt, g1, be1, xb);
  gemm8p<3, 3><<<dim3(16, 16), blk512, 0, stream>>>(
      xb, WTqkv, b_qkv, qb, kb, vbT, 4096, 3072, 1024, 11, rc, rsn);
  attn_kernel<1><<<dim3(16, 32), blk512, 0, stream>>>(qb, kb, vbT, at, 2048);
  gemm_bt<1, 64><<<dim3(8, 64), blk, 0, stream>>>(at, WTo, b_o, tgt, res,
                                                  nullptr, nullptr, 4096, 1024,
                                                  1024, 0, 1.f, nullptr,
                                                  nullptr);
  // --- cross-attention block
  ln_kernel<<<4096, blk, 0, stream>>>(res, g2, be2, xb);
  gemm_bt<4, 64><<<dim3(8, 64), blk, 0, stream>>>(
      xb, WTqc, bq_c, nullptr, qb, nullptr, nullptr, 4096, 1024, 1024, 11, QSC,
      nullptr, nullptr);
  gemm_bt<6, 64><<<dim3(8, 2, 2), blk, 0, stream>>>(
      memb, WTkc, bk_c, bv_c, kc, WTvc, vcT, 128, 1024, 1024, 6, 1.f, nullptr,
      nullptr);
  attn_kernel<0><<<dim3(16, 32), blk512, 0, stream>>>(qb, kc, vcT, at, 64);
  gemm_bt<1, 64><<<dim3(8, 64), blk, 0, stream>>>(at, WTco, b_co, res, res,
                                                  nullptr, nullptr, 4096, 1024,
                                                  1024, 0, 1.f, nullptr,
                                                  nullptr);
  // --- FFN block
  prep2<<<2048, blk, 0, stream>>>(W1, W2, WT1, WT2);
  ln_kernel<<<4096, blk, 0, stream>>>(res, g3, be3, xb);
  gemm8p<2, 4><<<dim3(16, 16), blk512, 0, stream>>>(xb, WT1, b1, ffh, nullptr,
                                                    nullptr, 4096, 4096, 1024,
                                                    0, nullptr, nullptr);
  gemm_bt<1, 64><<<dim3(8, 64), blk, 0, stream>>>(ffh, WT2, b2, res, res,
                                                  nullptr, nullptr, 4096, 1024,
                                                  4096, 0, 1.f, nullptr,
                                                  nullptr);
}

// Round 9
// 439.817 us; speedup vs baseline: 1.1216x; 1.0360x over previous
//
#include <hip/hip_runtime.h>

typedef unsigned short u16;
typedef short bf16x8 __attribute__((ext_vector_type(8)));
typedef float f32x4 __attribute__((ext_vector_type(4)));

#define HN 16
#define SD 64
#define SEQ 2048
#define DM 1024
#define QSC 0.18033688f  // 0.125 * log2(e): softmax done in exp2 domain

__device__ __forceinline__ float bf2f(u16 h) {
  return __uint_as_float(((unsigned int)h) << 16);
}
__device__ __forceinline__ u16 f2bf(float f) {
  unsigned int x = __float_as_uint(f);
  x += 0x7fffu + ((x >> 16) & 1u);
  return (u16)(x >> 16);
}
__device__ __forceinline__ float geluf(float x) {
  return 0.5f * x * (1.0f + erff(x * 0.70710678118654752f));
}
__device__ __forceinline__ void load_lds16(const u16* g, u16* l) {
  __builtin_amdgcn_global_load_lds(
      (const __attribute__((address_space(1))) void*)g,
      (__attribute__((address_space(3))) void*)l, 16, 0, 0);
}
// LDS byte offset of a generic pointer known to point into LDS.
__device__ __forceinline__ unsigned ldsoff(const u16* p) {
  return (unsigned)(unsigned long long)(
      const __attribute__((address_space(3))) u16*)p;
}

// ----------------------------------------------------- transpose tile (dev)
__device__ __forceinline__ void trans_tile(const float* __restrict__ in,
                                           u16* __restrict__ out, int K, int N,
                                           int tx, int ty, int tid,
                                           u16 (*T)[72]) {
  const int n0 = tx * 64, k0 = ty * 64;
#pragma unroll
  for (int it = 0; it < 2; ++it) {
    const int t = it * 256 + tid, r = t >> 3, c = (t & 7) * 8;
    const float* src = &in[(size_t)(k0 + r) * N + n0 + c];
    float4 d0 = *(const float4*)src;
    float4 d1 = *(const float4*)(src + 4);
    T[r][c + 0] = f2bf(d0.x);
    T[r][c + 1] = f2bf(d0.y);
    T[r][c + 2] = f2bf(d0.z);
    T[r][c + 3] = f2bf(d0.w);
    T[r][c + 4] = f2bf(d1.x);
    T[r][c + 5] = f2bf(d1.y);
    T[r][c + 6] = f2bf(d1.z);
    T[r][c + 7] = f2bf(d1.w);
  }
  __syncthreads();
#pragma unroll
  for (int it = 0; it < 2; ++it) {
    const int t = it * 256 + tid, r = t >> 3, c = (t & 7) * 8;
    uint4 d;
    u16* p = (u16*)&d;
#pragma unroll
    for (int j = 0; j < 8; ++j) p[j] = T[c + j][r];
    *(uint4*)&out[(size_t)(n0 + r) * K + k0 + c] = d;
  }
}

// ------------------------------------------------- prep1: 6 WT + mem f2b
__global__ __launch_bounds__(256) void prep1(
    const float* __restrict__ Wqkv, const float* __restrict__ Wo,
    const float* __restrict__ Wqc, const float* __restrict__ Wkc,
    const float* __restrict__ Wvc, const float* __restrict__ Wco,
    u16* __restrict__ Tqkv, u16* __restrict__ To, u16* __restrict__ Tqc,
    u16* __restrict__ Tkc, u16* __restrict__ Tvc, u16* __restrict__ Tco,
    const float* __restrict__ mem, u16* __restrict__ memb) {
  __shared__ u16 T[64][72];
  const int t = blockIdx.x, tid = threadIdx.x;
  if (t < 768) {
    trans_tile(Wqkv, Tqkv, 1024, 3072, t % 48, t / 48, tid, T);
    return;
  }
  if (t < 2048) {
    const int u = t - 768, m = u >> 8, sub = u & 255;
    const float* in;
    u16* out;
    if (m == 0) { in = Wo; out = To; }
    else if (m == 1) { in = Wqc; out = Tqc; }
    else if (m == 2) { in = Wkc; out = Tkc; }
    else if (m == 3) { in = Wvc; out = Tvc; }
    else { in = Wco; out = Tco; }
    trans_tile(in, out, 1024, 1024, sub & 15, sub >> 4, tid, T);
    return;
  }
  const int i = ((t - 2048) * 256 + tid) * 4;
  float4 d = *(const float4*)&mem[i];
  uint2 o;
  u16* po = (u16*)&o;
  po[0] = f2bf(d.x);
  po[1] = f2bf(d.y);
  po[2] = f2bf(d.z);
  po[3] = f2bf(d.w);
  *(uint2*)&memb[i] = o;
}

// ------------------------------------------------- prep2: W1 + W2 transpose
__global__ __launch_bounds__(256) void prep2(const float* __restrict__ W1,
                                             const float* __restrict__ W2,
                                             u16* __restrict__ T1,
                                             u16* __restrict__ T2) {
  __shared__ u16 T[64][72];
  const int t = blockIdx.x, tid = threadIdx.x;
  if (t < 1024) {
    trans_tile(W1, T1, 1024, 4096, t & 63, t >> 6, tid, T);
  } else {
    const int u = t - 1024;
    trans_tile(W2, T2, 4096, 1024, u & 15, u >> 4, tid, T);
  }
}

// ---------------------------------------------------------------- layernorm
__global__ __launch_bounds__(256) void ln_kernel(
    const float* __restrict__ x, const float* __restrict__ g,
    const float* __restrict__ be, u16* __restrict__ y) {
  const int row = blockIdx.x, tid = threadIdx.x;
  const float* xr = x + (size_t)row * DM;
  float4 d = *(const float4*)&xr[tid * 4];
  float v[4] = {d.x, d.y, d.z, d.w};
  float s1 = 0.f, s2 = 0.f;
#pragma unroll
  for (int j = 0; j < 4; ++j) {
    s1 += v[j];
    s2 += v[j] * v[j];
  }
#pragma unroll
  for (int dd = 1; dd < 64; dd <<= 1) {
    s1 += __shfl_xor(s1, dd, 64);
    s2 += __shfl_xor(s2, dd, 64);
  }
  __shared__ float p1[4], p2[4];
  const int lane = tid & 63, wv = tid >> 6;
  if (lane == 0) {
    p1[wv] = s1;
    p2[wv] = s2;
  }
  __syncthreads();
  s1 = p1[0] + p1[1] + p1[2] + p1[3];
  s2 = p2[0] + p2[1] + p2[2] + p2[3];
  const float mu = s1 * (1.f / DM);
  const float rs = rsqrtf(fmaxf(s2 * (1.f / DM) - mu * mu, 0.f) + 1e-5f);
  float4 gg = *(const float4*)&g[tid * 4];
  float4 bb = *(const float4*)&be[tid * 4];
  const float gv[4] = {gg.x, gg.y, gg.z, gg.w};
  const float bv[4] = {bb.x, bb.y, bb.z, bb.w};
  uint2 o;
  u16* po = (u16*)&o;
#pragma unroll
  for (int j = 0; j < 4; ++j) po[j] = f2bf((v[j] - mu) * rs * gv[j] + bv[j]);
  *(uint2*)&y[(size_t)row * DM + tid * 4] = o;
}

// ---------------------------------------------------------------- GEMM (r13)
// TM x 128 tile, BK=64, 4 waves, DOUBLE-BUFFERED with ONE barrier per K-tile
// (T3-minimum recipe): STAGE(t+1 -> buf^1) issued FIRST, asm ds_read frags of
// buf, lgkmcnt(0)+sched_barrier, MFMA, vmcnt(0), barrier.
template <int EPI, int TM>
__global__ __launch_bounds__(256) void gemm_bt(
    const u16* __restrict__ A, const u16* __restrict__ Bt,
    const float* __restrict__ bias, const float* __restrict__ resid,
    void* __restrict__ C0, u16* __restrict__ C1, u16* __restrict__ C2, int M,
    int N, int K, int rpbl, float sc, const float* __restrict__ rcos,
    const float* __restrict__ rsin) {
  constexpr int MI = TM / 32;
  __shared__ __align__(16) u16 As[2][TM][64];
  __shared__ __align__(16) u16 Bs[2][128][64];
  const int tid = threadIdx.x;
  const int lane = tid & 63, wv = tid >> 6;
  const int l16 = lane & 15, quad = lane >> 4;

  if (EPI == 6 && blockIdx.z) {
    Bt = (const u16*)C1;
    bias = resid;
  }

  int bx = blockIdx.x, by = blockIdx.y;
  const int gx = gridDim.x, gy = gridDim.y;
  if ((gy & 7) == 0) {
    const int f = by * gx + bx;
    const int c = f & 7, j = f >> 3;
    const int jm = j / gx;
    by = c * (gy >> 3) + jm;
    bx = j - jm * gx;
  }
  const int m0 = by * TM, n0 = bx * 128;
  const int wm = (wv >> 1) * (TM / 2), wn = (wv & 1) * 64;
  const int nk = K >> 6;

  const int srow = lane >> 3;
  const int sblk = (lane & 7) ^ srow;
  const u16* ag[MI];
  const u16* bg[4];
  u16* la[MI];
  u16* lb[4];
#pragma unroll
  for (int i = 0; i < MI; ++i) {
    const int r0 = i * 32 + wv * 8;
    ag[i] = A + (size_t)(m0 + r0 + srow) * K + sblk * 8;
    la[i] = &As[0][r0][0] + lane * 8;
  }
#pragma unroll
  for (int i = 0; i < 4; ++i) {
    const int r0 = i * 32 + wv * 8;
    bg[i] = Bt + (size_t)(n0 + r0 + srow) * K + sblk * 8;
    lb[i] = &Bs[0][r0][0] + lane * 8;
  }

  // fragment LDS byte addresses (buf0); buf adds literal imm in the asm.
  unsigned aad[2][MI], bad[2][4];
#pragma unroll
  for (int kk = 0; kk < 2; ++kk) {
#pragma unroll
    for (int mi = 0; mi < MI; ++mi) {
      const int row = wm + mi * 16 + l16;
      const int blk = (kk * 4 + quad) ^ (row & 7);
      aad[kk][mi] = ldsoff(&As[0][0][0]) + (unsigned)(row * 128 + blk * 16);
    }
#pragma unroll
    for (int ni = 0; ni < 4; ++ni) {
      const int row = wn + ni * 16 + l16;
      const int blk = (kk * 4 + quad) ^ (row & 7);
      bad[kk][ni] = ldsoff(&Bs[0][0][0]) + (unsigned)(row * 128 + blk * 16);
    }
  }

  f32x4 acc[MI][4] = {};

#define STB(P, ST)                                                            \
  {                                                                           \
    const int tt = (ST) < nk ? (ST) : nk - 1;                                 \
    const int k0s = tt << 6;                                                  \
    _Pragma("unroll") for (int i = 0; i < MI; ++i)                            \
        load_lds16(ag[i] + k0s, la[i] + (P) * (TM * 64));                     \
    _Pragma("unroll") for (int i = 0; i < 4; ++i)                             \
        load_lds16(bg[i] + k0s, lb[i] + (P) * 8192);                          \
  }

#define TILEB(CB, NP, ST)                                                     \
  {                                                                           \
    STB(NP, ST);                                                              \
    bf16x8 afr[2][MI], bfr[2][4];                                             \
    _Pragma("unroll") for (int kk = 0; kk < 2; ++kk) {                        \
      _Pragma("unroll") for (int mi = 0; mi < MI; ++mi)                       \
          asm volatile("ds_read_b128 %0, %1 offset:%2"                        \
                       : "=v"(afr[kk][mi])                                    \
                       : "v"(aad[kk][mi]), "i"((CB) * (TM * 128)));           \
      _Pragma("unroll") for (int ni = 0; ni < 4; ++ni)                        \
          asm volatile("ds_read_b128 %0, %1 offset:%2"                        \
                       : "=v"(bfr[kk][ni])                                    \
                       : "v"(bad[kk][ni]), "i"((CB)*16384));                  \
    }                                                                         \
    asm volatile("s_waitcnt lgkmcnt(0)");                                     \
    __builtin_amdgcn_sched_barrier(0);                                        \
    __builtin_amdgcn_s_setprio(1);                                            \
    _Pragma("unroll") for (int kk = 0; kk < 2; ++kk)                          \
        _Pragma("unroll") for (int mi = 0; mi < MI; ++mi)                     \
            _Pragma("unroll") for (int ni = 0; ni < 4; ++ni) acc[mi][ni] =    \
                __builtin_amdgcn_mfma_f32_16x16x32_bf16(                      \
                    afr[kk][mi], bfr[kk][ni], acc[mi][ni], 0, 0, 0);          \
    __builtin_amdgcn_s_setprio(0);                                            \
    asm volatile("s_waitcnt vmcnt(0)");                                       \
    __builtin_amdgcn_s_barrier();                                             \
  }

  STB(0, 0);
  asm volatile("s_waitcnt vmcnt(0)");
  __builtin_amdgcn_s_barrier();
  for (int t = 0; t < nk; t += 2) {  // nk even (16 or 64)
    TILEB(0, 1, t + 1)
    TILEB(1, 0, t + 2)
  }
#undef TILEB
#undef STB

  const int SL = 1 << rpbl;
#pragma unroll
  for (int mi = 0; mi < MI; ++mi) {
#pragma unroll
    for (int ni = 0; ni < 4; ++ni) {
#pragma unroll
      for (int r = 0; r < 4; ++r) {
        const int row = m0 + wm + mi * 16 + quad * 4 + r;
        const int col = n0 + wn + ni * 16 + l16;
        float vv = acc[mi][ni][r] + bias[col];
        if (EPI == 1) {
          vv += resid[(size_t)row * N + col];
          ((float*)C0)[(size_t)row * N + col] = vv;
        } else if (EPI == 2) {
          ((u16*)C0)[(size_t)row * N + col] = f2bf(geluf(vv));
        } else if (EPI == 3) {
          const float partner = __shfl_xor(vv, 1);
          const int which = col >> 10;
          const int nn = col & 1023;
          const int h = nn >> 6, hd = nn & 63;
          const int b = row >> rpbl;
          const int s = row & (SL - 1);
          if (which == 2) {
            C2[(((size_t)b * HN + h) * SD + hd) * SL + s] = f2bf(vv);
          } else {
            const int p = hd >> 1;
            const float cv = rcos[s * 32 + p];
            const float sv2 = rsin[s * 32 + p];
            float o = (hd & 1) ? (partner * sv2 + vv * cv)
                               : (vv * cv - partner * sv2);
            if (which == 0) o *= QSC;
            u16* dst = (which == 0) ? (u16*)C0 : C1;
            dst[(((size_t)b * HN + h) * SL + s) * SD + hd] = f2bf(o);
          }
        } else if (EPI == 4) {
          vv *= sc;
          const int h = col >> 6, hd = col & 63;
          const int b = row >> rpbl;
          const int s = row & (SL - 1);
          ((u16*)C0)[(((size_t)b * HN + h) * SL + s) * SD + hd] = f2bf(vv);
        } else if (EPI == 5) {
          const int h = col >> 6, hd = col & 63;
          const int b = row >> rpbl;
          const int s = row & (SL - 1);
          ((u16*)C0)[(((size_t)b * HN + h) * SD + hd) * SL + s] = f2bf(vv);
        } else if (EPI == 6) {
          const int h = col >> 6, hd = col & 63;
          const int b = row >> rpbl;
          const int s = row & (SL - 1);
          if (blockIdx.z == 0)
            ((u16*)C0)[(((size_t)b * HN + h) * SL + s) * SD + hd] = f2bf(vv);
          else
            C2[(((size_t)b * HN + h) * SD + hd) * SL + s] = f2bf(vv);
        } else {
          ((u16*)C0)[(size_t)row * N + col] = f2bf(vv);
        }
      }
    }
  }
}

// ---------------------------------------------------------------- GEMM 8p
// r16: r14 schedule with (a) ONE barrier per phase (pre-MFMA barrier removed:
// with a single barrier all waves share a phase window; every region's
// stage-write follows its last read by >=1 barrier -- w=r+1 proof in journal;
// vmcnt(8) retire chain unchanged, re-derived load-by-load) and (b) SPLIT
// lgkm waits: issue B reads, A-mh0, A-mh1; lgkmcnt(4) -> MFMA mh0 overlaps
// A-mh1 reads; lgkmcnt(0) -> MFMA mh1 (DS completes in order; rule #18
// sched_barrier after each wait).
template <int EPI, int NI>
__global__ __launch_bounds__(512, 2) void gemm8p(
    const u16* __restrict__ A, const u16* __restrict__ Bt,
    const float* __restrict__ bias, void* __restrict__ C0,
    u16* __restrict__ C1, u16* __restrict__ C2, int M, int N, int K, int rpbl,
    const float* __restrict__ rcos, const float* __restrict__ rsin) {
  __shared__ __align__(16) u16 L[4][2][8192];  // [A0,A1,B0,B1][buf][128x64]
  const int tid = threadIdx.x;
  const int lane = tid & 63, wv = tid >> 6;
  const int l16 = lane & 15, quad = lane >> 4;
  int bx = blockIdx.x, by = blockIdx.y;
  {  // bijective XCD chunk swizzle (nwg % 8 == 0 for all our grids)
    const int gx = gridDim.x;
    const int nwg = gx * gridDim.y;
    if ((nwg & 7) == 0) {
      const int f = by * gx + bx;
      const int q = nwg >> 3;
      const int wg = (f & 7) * q + (f >> 3);
      by = wg / gx;
      bx = wg - by * gx;
    }
  }
  const int m0 = by * 256, n0 = bx * (NI * 64);
  const int wm = (wv >> 2) * 128, wn = (wv & 3) * (NI * 16);
  const int nk = K >> 6;

  const u16* Ag = A + (size_t)m0 * K;
  const u16* Bg = Bt + (size_t)n0 * K;

#define STAGE(MAT, H, ST, P)                                                  \
  {                                                                           \
    const int tt = (ST) < nk ? (ST) : nk - 1; /* clamp: dummy loads */        \
    const int k0s = tt << 6;                                                  \
    u16* dst = &L[(MAT)*2 + (H)][P][0];                                       \
    const u16* srcp = (MAT) ? Bg : Ag;                                        \
    _Pragma("unroll") for (int j = 0; j < 2; ++j) {                           \
      const int li = wv * 2 + j;                                              \
      const int pr = li * 8 + (lane >> 3);                                    \
      const int bb = lane & 7;                                                \
      const int gg2 = bb ^ (pr & 7);                                          \
      const int rw = 2 * pr + (gg2 >> 2);                                     \
      load_lds16(srcp + (size_t)rw * K + k0s + (H)*32 + (gg2 & 3) * 8,        \
                 dst + li * 512 + lane * 8);                                  \
    }                                                                         \
  }

  unsigned aaddr[2][4], baddr[NI];
  {
    const unsigned Lb = ldsoff(&L[0][0][0]);
#pragma unroll
    for (int MH = 0; MH < 2; ++MH)
#pragma unroll
      for (int mi = 0; mi < 4; ++mi) {
        const int R = wm + MH * 64 + mi * 16 + l16;
        const int p = R >> 1, g = (R & 1) * 4 + quad, b = g ^ (p & 7);
        aaddr[MH][mi] = Lb + (unsigned)(p * 64 + b * 8) * 2u;
      }
#pragma unroll
    for (int ni = 0; ni < NI; ++ni) {
      const int R = wn + ni * 16 + l16;
      const int p = R >> 1, g = (R & 1) * 4 + quad, b = g ^ (p & 7);
      baddr[ni] = Lb + 65536u + (unsigned)(p * 64 + b * 8) * 2u;
    }
  }

  f32x4 acc[8][NI] = {};

// One phase: issue B reads, A-mh0, A-mh1 (in order), 2 stages; lgkmcnt(4) ->
// MFMA mh0 (A-mh1 reads drain underneath); lgkmcnt(0) -> MFMA mh1;
// counted vmcnt(8); ONE barrier.
#define PHASE(CB, KK, S1M, S1H, S2M, S2H, ST, SP)                             \
  {                                                                           \
    bf16x8 af[2][4];                                                          \
    bf16x8 bfr[NI];                                                           \
    _Pragma("unroll") for (int ni = 0; ni < NI; ++ni)                         \
        asm volatile("ds_read_b128 %0, %1 offset:%2"                          \
                     : "=v"(bfr[ni])                                          \
                     : "v"(baddr[ni]), "i"((KK)*32768 + (CB)*16384));         \
    _Pragma("unroll") for (int mh = 0; mh < 2; ++mh)                          \
        _Pragma("unroll") for (int mi = 0; mi < 4; ++mi)                      \
            asm volatile("ds_read_b128 %0, %1 offset:%2"                      \
                         : "=v"(af[mh][mi])                                   \
                         : "v"(aaddr[mh][mi]),                                \
                           "i"((KK)*32768 + (CB)*16384));                     \
    STAGE(S1M, S1H, ST, SP);                                                  \
    STAGE(S2M, S2H, ST, SP);                                                  \
    asm volatile("s_waitcnt lgkmcnt(4)");                                     \
    __builtin_amdgcn_sched_barrier(0);                                        \
    __builtin_amdgcn_s_setprio(1);                                            \
    _Pragma("unroll") for (int mi = 0; mi < 4; ++mi)                          \
        _Pragma("unroll") for (int ni = 0; ni < NI; ++ni)                     \
            acc[mi][ni] = __builtin_amdgcn_mfma_f32_16x16x32_bf16(            \
                af[0][mi], bfr[ni], acc[mi][ni], 0, 0, 0);                    \
    asm volatile("s_waitcnt lgkmcnt(0)");                                     \
    __builtin_amdgcn_sched_barrier(0);                                        \
    _Pragma("unroll") for (int mi = 0; mi < 4; ++mi)                          \
        _Pragma("unroll") for (int ni = 0; ni < NI; ++ni)                     \
            acc[4 + mi][ni] = __builtin_amdgcn_mfma_f32_16x16x32_bf16(        \
                af[1][mi], bfr[ni], acc[4 + mi][ni], 0, 0, 0);                \
    __builtin_amdgcn_s_setprio(0);                                            \
    asm volatile("s_waitcnt vmcnt(8)");                                       \
    __builtin_amdgcn_s_barrier();                                             \
  }

  // prologue: A0B0(t0), A1B1(t0), A0B0(t1) = 12 loads/thread; retire first 4
  // (A0B0(t0)) via vmcnt(8).
  STAGE(0, 0, 0, 0);
  STAGE(1, 0, 0, 0);
  STAGE(0, 1, 0, 0);
  STAGE(1, 1, 0, 0);
  STAGE(0, 0, 1, 1);
  STAGE(1, 0, 1, 1);
  asm volatile("s_waitcnt vmcnt(8)");
  __builtin_amdgcn_s_barrier();

  for (int t = 0; t < nk; t += 2) {  // nk even for all our shapes
    PHASE(0, 0, 0, 1, 1, 1, t + 1, 1)
    PHASE(0, 1, 0, 0, 1, 0, t + 2, 0)
    PHASE(1, 0, 0, 1, 1, 1, t + 2, 0)
    PHASE(1, 1, 0, 0, 1, 0, t + 3, 1)
  }
#undef PHASE
#undef STAGE

  const int SL = 1 << rpbl;
#pragma unroll
  for (int mi = 0; mi < 8; ++mi) {
#pragma unroll
    for (int ni = 0; ni < NI; ++ni) {
#pragma unroll
      for (int r = 0; r < 4; ++r) {
        const int row = m0 + wm + mi * 16 + quad * 4 + r;
        const int col = n0 + wn + ni * 16 + l16;
        float vv = acc[mi][ni][r] + bias[col];
        if (EPI == 2) {
          ((u16*)C0)[(size_t)row * N + col] = f2bf(geluf(vv));
        } else if (EPI == 3) {
          const float partner = __shfl_xor(vv, 1);
          const int which = col >> 10;
          const int nn = col & 1023;
          const int h = nn >> 6, hd = nn & 63;
          const int b = row >> rpbl;
          const int s = row & (SL - 1);
          if (which == 2) {
            C2[(((size_t)b * HN + h) * SD + hd) * SL + s] = f2bf(vv);
          } else {
            const int p = hd >> 1;
            const float cv = rcos[s * 32 + p];
            const float sv2 = rsin[s * 32 + p];
            float o = (hd & 1) ? (partner * sv2 + vv * cv)
                               : (vv * cv - partner * sv2);
            if (which == 0) o *= QSC;
            u16* dst = (which == 0) ? (u16*)C0 : C1;
            dst[(((size_t)b * HN + h) * SL + s) * SD + hd] = f2bf(o);
          }
        } else {
          ((u16*)C0)[(size_t)row * N + col] = f2bf(vv);
        }
      }
    }
  }
}

// ---------------------------------------------------------------- attention
// r15: XCD head-affine swizzle + XOR-block LDS swizzle + K/V reg prefetch.
template <int CAUSAL>
__global__ __launch_bounds__(512, 4) void attn_kernel(
    const u16* __restrict__ q, const u16* __restrict__ k,
    const u16* __restrict__ vt, u16* __restrict__ out, int kv_len) {
  __shared__ __align__(16) u16 Qs[128][64], Ks[64][64], VTs[64][64];
  __shared__ __align__(16) u16 Ps[128][64];
  const int tid = threadIdx.x;
  const int lane = tid & 63, wv = tid >> 6;
  const int t2 = wv >> 2, w4 = wv & 3;
  const int l16 = lane & 15, quad = lane >> 4;
  int bx, bh;
  {
    const int l = blockIdx.y * 16 + blockIdx.x;
    const int c = l & 7, j = l >> 3;
    bh = c + 8 * (j >> 4);
    bx = j & 15;
  }
  const int qtA = bx;
  const int qtB = CAUSAL ? (31 - bx) : (bx + 16);
  const int qt = t2 ? qtB : qtA;
  const u16* qb = q + (size_t)bh * SEQ * SD;
  const u16* kb = k + (size_t)bh * kv_len * SD;
  const u16* vtb = vt + (size_t)bh * SD * kv_len;

#pragma unroll
  for (int it = 0; it < 2; ++it) {
    const int t = it * 512 + tid, r = t >> 3, cb = t & 7;
    const int qrow = (r < 64) ? (qtA * 64 + r) : (qtB * 64 + (r - 64));
    *(uint4*)&Qs[r][(cb ^ (r & 7)) * 8] =
        *(const uint4*)&qb[(size_t)qrow * SD + cb * 8];
  }

  f32x4 o_acc[4] = {};
  float l_i[4] = {};

  const int ktiles = CAUSAL ? (qtB + 1) : ((kv_len + 63) >> 6);
  const int sr = tid >> 3, scb = tid & 7;
  const int swb = (scb ^ (sr & 7)) * 8;

  uint4 kd = *(const uint4*)&kb[(size_t)sr * SD + scb * 8];
  uint4 vd = *(const uint4*)&vtb[(size_t)sr * kv_len + scb * 8];

  for (int kt = 0; kt < ktiles; ++kt) {
    __syncthreads();
    *(uint4*)&Ks[sr][swb] = kd;
    *(uint4*)&VTs[sr][swb] = vd;
    __syncthreads();
    if (kt + 1 < ktiles) {  // prefetch: in flight across compute
      kd = *(const uint4*)&kb[((size_t)(kt + 1) * 64 + sr) * SD + scb * 8];
      vd = *(const uint4*)&vtb[(size_t)sr * kv_len + (kt + 1) * 64 + scb * 8];
    }

    if (kt <= qt) {  // wave-uniform causal participation
      const int roff = t2 * 64 + w4 * 16;
      const int qrw = roff + l16;
      f32x4 s_acc[4] = {};
#pragma unroll
      for (int kk = 0; kk < 2; ++kk) {
        const bf16x8 aq =
            *(const bf16x8*)&Qs[qrw][((kk * 4 + quad) ^ (qrw & 7)) * 8];
#pragma unroll
        for (int ni = 0; ni < 4; ++ni) {
          const int krw = ni * 16 + l16;
          const bf16x8 bk =
              *(const bf16x8*)&Ks[krw][((kk * 4 + quad) ^ (krw & 7)) * 8];
          s_acc[ni] = __builtin_amdgcn_mfma_f32_16x16x32_bf16(aq, bk, s_acc[ni],
                                                              0, 0, 0);
        }
      }
      float rsum[4] = {0.f, 0.f, 0.f, 0.f};
      const bool dg = CAUSAL && (kt == qt);
#pragma unroll
      for (int ni = 0; ni < 4; ++ni) {
        const int colb = ni * 2 + (l16 >> 3);
#pragma unroll
        for (int r = 0; r < 4; ++r) {
          float sv = s_acc[ni][r];
          if (dg && (ni * 16 + l16 > w4 * 16 + quad * 4 + r)) sv = -1e9f;
          const float pe = __builtin_amdgcn_exp2f(sv);
          rsum[r] += pe;
          const int prow = wv * 16 + quad * 4 + r;
          Ps[prow][((colb ^ (prow & 7)) * 8) + (l16 & 7)] =
              (u16)(__float_as_uint(pe) >> 16);
        }
      }
#pragma unroll
      for (int r = 0; r < 4; ++r) {
#pragma unroll
        for (int dd = 1; dd < 16; dd <<= 1)
          rsum[r] += __shfl_xor(rsum[r], dd, 64);
        l_i[r] += rsum[r];
      }
      const int prw = wv * 16 + l16;
#pragma unroll
      for (int kk = 0; kk < 2; ++kk) {
        const bf16x8 ap =
            *(const bf16x8*)&Ps[prw][((kk * 4 + quad) ^ (prw & 7)) * 8];
#pragma unroll
        for (int ni = 0; ni < 4; ++ni) {
          const int vrw = ni * 16 + l16;
          const bf16x8 bv =
              *(const bf16x8*)&VTs[vrw][((kk * 4 + quad) ^ (vrw & 7)) * 8];
          o_acc[ni] = __builtin_amdgcn_mfma_f32_16x16x32_bf16(ap, bv, o_acc[ni],
                                                              0, 0, 0);
        }
      }
    }
  }

  const int b = bh >> 4, h = bh & 15;
#pragma unroll
  for (int r = 0; r < 4; ++r) {
    const float inv = 1.f / l_i[r];
    const int s = qt * 64 + w4 * 16 + quad * 4 + r;
#pragma unroll
    for (int ni = 0; ni < 4; ++ni)
      out[((size_t)b * SEQ + s) * DM + h * SD + ni * 16 + l16] =
          f2bf(o_acc[ni][r] * inv);
  }
}

// ---------------------------------------------------------------- launch
extern "C" void kernel_launch(void* const* d_in, const int* in_sizes, int n_in,
                              void* d_out, int out_size, void* d_ws,
                              size_t ws_size, hipStream_t stream) {
  (void)in_sizes;
  (void)n_in;
  (void)out_size;
  (void)ws_size;
  const float* tgt = (const float*)d_in[0];
  const float* mem = (const float*)d_in[1];
  const float* rc = (const float*)d_in[2];
  const float* rsn = (const float*)d_in[3];
  const float* W_qkv = (const float*)d_in[4];
  const float* b_qkv = (const float*)d_in[5];
  const float* W_o = (const float*)d_in[6];
  const float* b_o = (const float*)d_in[7];
  const float* Wq_c = (const float*)d_in[8];
  const float* bq_c = (const float*)d_in[9];
  const float* Wk_c = (const float*)d_in[10];
  const float* bk_c = (const float*)d_in[11];
  const float* Wv_c = (const float*)d_in[12];
  const float* bv_c = (const float*)d_in[13];
  const float* W_co = (const float*)d_in[14];
  const float* b_co = (const float*)d_in[15];
  const float* W1 = (const float*)d_in[16];
  const float* b1 = (const float*)d_in[17];
  const float* W2 = (const float*)d_in[18];
  const float* b2 = (const float*)d_in[19];
  const float* g1 = (const float*)d_in[20];
  const float* be1 = (const float*)d_in[21];
  const float* g2 = (const float*)d_in[22];
  const float* be2 = (const float*)d_in[23];
  const float* g3 = (const float*)d_in[24];
  const float* be3 = (const float*)d_in[25];

  const size_t M1 = 1048576;
  u16* w = (u16*)d_ws;
  u16* WTqkv = w;
  u16* WTo = w + 3 * M1;
  u16* WTqc = w + 4 * M1;
  u16* WTkc = w + 5 * M1;
  u16* WTvc = w + 6 * M1;
  u16* WTco = w + 7 * M1;
  u16* WT1 = w;
  u16* WT2 = w + 4 * M1;
  u16* xb = w + 8 * M1;
  u16* qb = w + 12 * M1;
  u16* kb = w + 16 * M1;
  u16* vbT = w + 20 * M1;
  u16* at = w + 24 * M1;
  u16* kc = w + 28 * M1;
  u16* vcT = kc + 131072;
  u16* memb = vcT + 131072;
  u16* ffh = qb;
  float* res = (float*)d_out;

  dim3 blk(256), blk512(512);
  prep1<<<2176, blk, 0, stream>>>(W_qkv, W_o, Wq_c, Wk_c, Wv_c, W_co, WTqkv,
                                  WTo, WTqc, WTkc, WTvc, WTco, mem, memb);

  // --- self-attention block
  ln_kernel<<<4096, blk, 0, stream>>>(tgt, g1, be1, xb);
  gemm8p<3, 3><<<dim3(16, 16), blk512, 0, stream>>>(
      xb, WTqkv, b_qkv, qb, kb, vbT, 4096, 3072, 1024, 11, rc, rsn);
  attn_kernel<1><<<dim3(16, 32), blk512, 0, stream>>>(qb, kb, vbT, at, 2048);
  gemm_bt<1, 64><<<dim3(8, 64), blk, 0, stream>>>(at, WTo, b_o, tgt, res,
                                                  nullptr, nullptr, 4096, 1024,
                                                  1024, 0, 1.f, nullptr,
                                                  nullptr);
  // --- cross-attention block
  ln_kernel<<<4096, blk, 0, stream>>>(res, g2, be2, xb);
  gemm_bt<4, 64><<<dim3(8, 64), blk, 0, stream>>>(
      xb, WTqc, bq_c, nullptr, qb, nullptr, nullptr, 4096, 1024, 1024, 11, QSC,
      nullptr, nullptr);
  gemm_bt<6, 64><<<dim3(8, 2, 2), blk, 0, stream>>>(
      memb, WTkc, bk_c, bv_c, kc, WTvc, vcT, 128, 1024, 1024, 6, 1.f, nullptr,
      nullptr);
  attn_kernel<0><<<dim3(16, 32), blk512, 0, stream>>>(qb, kc, vcT, at, 64);
  gemm_bt<1, 64><<<dim3(8, 64), blk, 0, stream>>>(at, WTco, b_co, res, res,
                                                  nullptr, nullptr, 4096, 1024,
                                                  1024, 0, 1.f, nullptr,
                                                  nullptr);
  // --- FFN block
  prep2<<<2048, blk, 0, stream>>>(W1, W2, WT1, WT2);
  ln_kernel<<<4096, blk, 0, stream>>>(res, g3, be3, xb);
  gemm8p<2, 4><<<dim3(16, 16), blk512, 0, stream>>>(xb, WT1, b1, ffh, nullptr,
                                                    nullptr, 4096, 4096, 1024,
                                                    0, nullptr, nullptr);
  gemm_bt<1, 64><<<dim3(8, 64), blk, 0, stream>>>(ffh, WT2, b2, res, res,
                                                  nullptr, nullptr, 4096, 1024,
                                                  4096, 0, 1.f, nullptr,
                                                  nullptr);
}